// Round 1
// baseline (1137.394 us; speedup 1.0000x reference)
//
#include <hip/hip_runtime.h>
#include <math.h>

#define NSEQ   3136      // N0 = 56*56
#define NTOK   25088     // B * NSEQ
#define BATCH  8
#define WID    56
#define NHEADS 8
#define HDIM   32
#define CDIM   256
#define PLEN   49
#define NENT   58        // 9 local + 49 pool
#define NEGC  -1000000000.0f

__device__ __forceinline__ float gelu_exact(float x) {
    return 0.5f * x * (1.0f + erff(x * 0.70710678118654752440f));
}

// ---------------------------------------------------------------------------
// Tiled fp32 GEMM: C = A(MxK) @ B(KxN) + bias, optional exact-GELU epilogue.
// 64x64 tile, BK=16, 256 threads, 4x4 accum per thread.
// ---------------------------------------------------------------------------
template<int ACT>
__global__ __launch_bounds__(256) void gemm_bias(
    const float* __restrict__ A, const float* __restrict__ Bw,
    const float* __restrict__ bias, float* __restrict__ C,
    int M, int N, int K)
{
    __shared__ float As[16][68];   // [k][m], row stride 68 floats (16B aligned)
    __shared__ float Bs[16][68];   // [k][n]
    const int tid = threadIdx.x;
    const int tx  = tid & 15, ty = tid >> 4;
    const int bm  = blockIdx.y * 64, bn = blockIdx.x * 64;
    float acc[4][4] = {};

    const int am  = tid >> 2;          // 0..63  A-tile row
    const int ak  = (tid & 3) * 4;     // 0..12  A-tile col (x4)
    const int bk  = tid >> 4;          // 0..15  B-tile row
    const int bn4 = (tid & 15) * 4;    // 0..60  B-tile col (x4)

    for (int k0 = 0; k0 < K; k0 += 16) {
        float4 av = make_float4(0.f, 0.f, 0.f, 0.f);
        if (bm + am < M)
            av = *reinterpret_cast<const float4*>(&A[(size_t)(bm + am) * K + k0 + ak]);
        As[ak+0][am] = av.x; As[ak+1][am] = av.y; As[ak+2][am] = av.z; As[ak+3][am] = av.w;

        float4 bv = *reinterpret_cast<const float4*>(&Bw[(size_t)(k0 + bk) * N + bn + bn4]);
        Bs[bk][bn4+0] = bv.x; Bs[bk][bn4+1] = bv.y; Bs[bk][bn4+2] = bv.z; Bs[bk][bn4+3] = bv.w;
        __syncthreads();

        #pragma unroll
        for (int kk = 0; kk < 16; kk++) {
            float a0 = As[kk][ty*4+0], a1 = As[kk][ty*4+1], a2 = As[kk][ty*4+2], a3 = As[kk][ty*4+3];
            float b0 = Bs[kk][tx*4+0], b1 = Bs[kk][tx*4+1], b2 = Bs[kk][tx*4+2], b3 = Bs[kk][tx*4+3];
            acc[0][0] += a0*b0; acc[0][1] += a0*b1; acc[0][2] += a0*b2; acc[0][3] += a0*b3;
            acc[1][0] += a1*b0; acc[1][1] += a1*b1; acc[1][2] += a1*b2; acc[1][3] += a1*b3;
            acc[2][0] += a2*b0; acc[2][1] += a2*b1; acc[2][2] += a2*b2; acc[2][3] += a2*b3;
            acc[3][0] += a3*b0; acc[3][1] += a3*b1; acc[3][2] += a3*b2; acc[3][3] += a3*b3;
        }
        __syncthreads();
    }

    const int n0 = bn + tx * 4;
    float4 bsv = *reinterpret_cast<const float4*>(&bias[n0]);
    #pragma unroll
    for (int r = 0; r < 4; r++) {
        int m = bm + ty * 4 + r;
        if (m < M) {
            float4 o;
            o.x = acc[r][0] + bsv.x;
            o.y = acc[r][1] + bsv.y;
            o.z = acc[r][2] + bsv.z;
            o.w = acc[r][3] + bsv.w;
            if (ACT == 1) {
                o.x = gelu_exact(o.x); o.y = gelu_exact(o.y);
                o.z = gelu_exact(o.z); o.w = gelu_exact(o.w);
            }
            *reinterpret_cast<float4*>(&C[(size_t)m * N + n0]) = o;
        }
    }
}

// ---------------------------------------------------------------------------
// In-place L2-normalize each 32-dim head group of the first 256 columns of a
// row. One block (256 threads) per row. Group boundaries align with 32-lane
// shuffle halves, so masks 16..1 reduce within exactly one head group.
// ---------------------------------------------------------------------------
__global__ __launch_bounds__(256) void l2norm_groups(float* __restrict__ buf, int rowStride)
{
    size_t row = blockIdx.x;
    int c = threadIdx.x;
    size_t idx = row * (size_t)rowStride + c;
    float v = buf[idx];
    float ss = v * v;
    #pragma unroll
    for (int m = 16; m > 0; m >>= 1) ss += __shfl_xor(ss, m);
    float denom = fmaxf(sqrtf(ss), 1e-12f);
    buf[idx] = v / denom;
}

// ---------------------------------------------------------------------------
// 8x8 average pool of gelu'd sr output + LayerNorm. One block per (b, p).
// ---------------------------------------------------------------------------
__global__ __launch_bounds__(256) void pool_ln(
    const float* __restrict__ xs, const float* __restrict__ g,
    const float* __restrict__ bb, float* __restrict__ xp)
{
    int b = blockIdx.x / PLEN, p = blockIdx.x % PLEN;
    int ph = p / 7, pw = p % 7;
    int c = threadIdx.x;
    float s = 0.f;
    #pragma unroll
    for (int i = 0; i < 8; i++) {
        int rowpix = (ph * 8 + i) * WID + pw * 8;
        const float* base = &xs[((size_t)b * NSEQ + rowpix) * CDIM + c];
        #pragma unroll
        for (int jj = 0; jj < 8; jj++) s += base[(size_t)jj * CDIM];
    }
    s *= (1.f / 64.f);

    float ssum = s, ssq = s * s;
    #pragma unroll
    for (int m = 32; m > 0; m >>= 1) {
        ssum += __shfl_xor(ssum, m);
        ssq  += __shfl_xor(ssq, m);
    }
    __shared__ float r1[4], r2[4];
    int wv = threadIdx.x >> 6;
    if ((threadIdx.x & 63) == 0) { r1[wv] = ssum; r2[wv] = ssq; }
    __syncthreads();
    float tsum = r1[0] + r1[1] + r1[2] + r1[3];
    float tsq  = r2[0] + r2[1] + r2[2] + r2[3];
    float mu  = tsum * (1.f / 256.f);
    float var = tsq * (1.f / 256.f) - mu * mu;
    float o = (s - mu) * rsqrtf(var + 1e-5f) * g[c] + bb[c];
    xp[(size_t)blockIdx.x * CDIM + c] = o;
}

// ---------------------------------------------------------------------------
// CPB MLP table: tab[t,h] = relu(rct[t,:] @ fc1 + b1) @ fc2[:,h] + b2[h]
// One thread per (t, h); hidden recomputed per head (tiny: 84 MFLOP total).
// ---------------------------------------------------------------------------
__global__ __launch_bounds__(256) void cpb_tab_kernel(
    const float* __restrict__ rct, const float* __restrict__ fc1w,
    const float* __restrict__ fc1b, const float* __restrict__ fc2w,
    const float* __restrict__ fc2b, float* __restrict__ tab)
{
    int gid = blockIdx.x * 256 + threadIdx.x;
    if (gid >= 4096 * 8) return;
    int t = gid >> 3, h = gid & 7;
    float c0 = rct[t * 2 + 0], c1 = rct[t * 2 + 1];
    float acc = 0.f;
    for (int i = 0; i < 512; i++) {
        float hid = fmaxf(c0 * fc1w[i] + c1 * fc1w[512 + i] + fc1b[i], 0.f);
        acc += hid * fc2w[i * 8 + h];
    }
    tab[t * 8 + h] = acc + fc2b[h];
}

// ---------------------------------------------------------------------------
// Fused attention: one wave per (b, h, n) row. Half-waves split the 58
// score/output entries (stride 2); 32-lane shuffle dot products over HD=32.
// qs is derived on the fly from q_norm. pool_bias gathered from tab via rpi
// (both jax resizes are identity: pH==PH0==7, H==H0==56).
// ---------------------------------------------------------------------------
__global__ __launch_bounds__(256) void attn_fused(
    const float* __restrict__ qn,   // (B,N,256)  L2-normalized q
    const float* __restrict__ kvb,  // (B,N,512)  [k normalized | v]
    const float* __restrict__ kvp,  // (B,49,512) [k_pool normalized | v_pool]
    const float* __restrict__ tab,  // (4096,8)
    const int*   __restrict__ rpi,  // (N*49)
    const float* __restrict__ qe,   // (8,32)
    const float* __restrict__ temp, // (8)
    const float* __restrict__ sls,  // (1)
    const float* __restrict__ rpb,  // (8,9)
    const float* __restrict__ lt,   // (8,32,9)
    const float* __restrict__ lb,   // (8,9)
    float* __restrict__ attout)     // (B,N,256)
{
    const int wid  = threadIdx.x >> 6;
    const int lane = threadIdx.x & 63;
    const int hw   = lane >> 5;
    const int d    = lane & 31;
    int r  = blockIdx.x * 4 + wid;          // (b*8 + h)*N + n
    int n  = r % NSEQ;
    int bh = r / NSEQ;
    int h  = bh & 7;
    int b  = bh >> 3;
    int i  = n / WID, j = n % WID;

    __shared__ float sS[4][64];
    __shared__ float sLT[4][12];

    float scale = log1pf(expf(temp[h])) * sls[0];
    float qnv = qn[((size_t)(b * NSEQ + n)) * CDIM + h * HDIM + d];
    float qsv = (qnv + qe[h * HDIM + d]) * scale;

    // learnable-token dots for the 9 local entries (post-softmax add)
    #pragma unroll
    for (int e0 = 0; e0 < 10; e0 += 2) {
        int e = e0 + hw;
        float v_ = (e < 9) ? qnv * lt[(h * HDIM + d) * 9 + e] : 0.f;
        #pragma unroll
        for (int m = 16; m > 0; m >>= 1) v_ += __shfl_xor(v_, m);
        if (d == 0 && e < 9) sLT[wid][e] = v_ + lb[h * 9 + e];
    }

    // scores: 9 local (window) + 49 pool
    for (int e0 = 0; e0 < NENT; e0 += 2) {
        int e = e0 + hw;
        const float* kp;
        float bias;
        bool valid = true;
        if (e < 9) {
            int ii = i + e / 3 - 1, jj = j + (e % 3) - 1;
            valid = (ii >= 0 && ii < WID && jj >= 0 && jj < WID);
            int nn = min(max(ii, 0), WID - 1) * WID + min(max(jj, 0), WID - 1);
            kp = &kvb[((size_t)(b * NSEQ + nn)) * 512 + h * HDIM];
            bias = rpb[h * 9 + e];
        } else {
            int mm = e - 9;
            kp = &kvp[((size_t)(b * PLEN + mm)) * 512 + h * HDIM];
            bias = tab[rpi[n * PLEN + mm] * 8 + h];
        }
        float dot = qsv * kp[d];
        #pragma unroll
        for (int m = 16; m > 0; m >>= 1) dot += __shfl_xor(dot, m);
        float sc = valid ? (dot + bias) : NEGC;
        if (d == 0) sS[wid][e] = sc;
    }
    __syncthreads();

    // softmax over 58 entries, then post-softmax learnable add on local
    float sc = (lane < NENT) ? sS[wid][lane] : -INFINITY;
    float mx = sc;
    #pragma unroll
    for (int m = 32; m > 0; m >>= 1) mx = fmaxf(mx, __shfl_xor(mx, m));
    float p = (lane < NENT) ? expf(sc - mx) : 0.f;
    float sum = p;
    #pragma unroll
    for (int m = 32; m > 0; m >>= 1) sum += __shfl_xor(sum, m);
    float a = p / sum;
    if (lane < 9)    a += sLT[wid][lane];
    if (lane < NENT) sS[wid][lane] = a;
    __syncthreads();

    // weighted sum of v (local masked to 0 where invalid) + v_pool
    float acc = 0.f;
    for (int e0 = 0; e0 < NENT; e0 += 2) {
        int e = e0 + hw;
        float av = sS[wid][e];
        const float* vp;
        bool valid = true;
        if (e < 9) {
            int ii = i + e / 3 - 1, jj = j + (e % 3) - 1;
            valid = (ii >= 0 && ii < WID && jj >= 0 && jj < WID);
            int nn = min(max(ii, 0), WID - 1) * WID + min(max(jj, 0), WID - 1);
            vp = &kvb[((size_t)(b * NSEQ + nn)) * 512 + 256 + h * HDIM];
        } else {
            vp = &kvp[((size_t)(b * PLEN + (e - 9))) * 512 + 256 + h * HDIM];
        }
        float vv = valid ? vp[d] : 0.f;
        acc += av * vv;
    }
    acc += __shfl_xor(acc, 32);
    if (lane < 32)
        attout[((size_t)(b * NSEQ + n)) * CDIM + h * HDIM + d] = acc;
}

// ---------------------------------------------------------------------------
// Workspace layout (floats):
//   qn   @ 0         : 6,422,528   (B,N,256)   q -> normalized in place
//   kvb  @ 6422528   : 12,845,056  (B,N,512)   k(normalized in place) | v
//   xs   @ 19267584  : 6,422,528   (B,N,256)   gelu(sr) ; reused as attout
//   xp   @ 25690112  : 100,352     (B,49,256)
//   kvp  @ 25790464  : 200,704     (B,49,512)
//   tab  @ 25991168  : 32,768      (4096,8)
// total 26,023,936 floats = 104.1 MB
// ---------------------------------------------------------------------------
extern "C" void kernel_launch(void* const* d_in, const int* in_sizes, int n_in,
                              void* d_out, int out_size, void* d_ws, size_t ws_size,
                              hipStream_t stream)
{
    const float* x    = (const float*)d_in[0];
    const float* sls  = (const float*)d_in[1];
    const float* rct  = (const float*)d_in[2];
    const float* q_w  = (const float*)d_in[3];
    const float* q_b  = (const float*)d_in[4];
    const float* qe   = (const float*)d_in[5];
    const float* temp = (const float*)d_in[6];
    const float* kv_w = (const float*)d_in[7];
    const float* kv_b = (const float*)d_in[8];
    const float* sr_w = (const float*)d_in[9];
    const float* sr_b = (const float*)d_in[10];
    const float* ng   = (const float*)d_in[11];
    const float* nb   = (const float*)d_in[12];
    const float* f1w  = (const float*)d_in[13];
    const float* f1b  = (const float*)d_in[14];
    const float* f2w  = (const float*)d_in[15];
    const float* f2b  = (const float*)d_in[16];
    const float* rpb  = (const float*)d_in[17];
    const float* lt   = (const float*)d_in[18];
    const float* lb   = (const float*)d_in[19];
    const float* pw   = (const float*)d_in[20];
    const float* pbi  = (const float*)d_in[21];
    const int*   rpi  = (const int*)d_in[22];

    if (ws_size < (size_t)26023936 * sizeof(float)) return;

    float* ws  = (float*)d_ws;
    float* qn  = ws;
    float* kvb = ws + 6422528;
    float* xs  = ws + 19267584;
    float* xp  = ws + 25690112;
    float* kvp = ws + 25790464;
    float* tab = ws + 25991168;
    float* out = (float*)d_out;

    dim3 blk(256);

    // q projection -> normalize per head in place
    gemm_bias<0><<<dim3(4, 392), blk, 0, stream>>>(x, q_w, q_b, qn, NTOK, 256, 256);
    l2norm_groups<<<NTOK, blk, 0, stream>>>(qn, 256);

    // kv projection -> normalize k half in place
    gemm_bias<0><<<dim3(8, 392), blk, 0, stream>>>(x, kv_w, kv_b, kvb, NTOK, 512, 256);
    l2norm_groups<<<NTOK, blk, 0, stream>>>(kvb, 512);

    // sr projection + exact GELU
    gemm_bias<1><<<dim3(4, 392), blk, 0, stream>>>(x, sr_w, sr_b, xs, NTOK, 256, 256);

    // 8x8 average pool + LayerNorm
    pool_ln<<<BATCH * PLEN, blk, 0, stream>>>(xs, ng, nb, xp);

    // pooled kv projection -> normalize k half in place
    gemm_bias<0><<<dim3(8, 7), blk, 0, stream>>>(xp, kv_w, kv_b, kvp, BATCH * PLEN, 512, 256);
    l2norm_groups<<<BATCH * PLEN, blk, 0, stream>>>(kvp, 512);

    // CPB bias table
    cpb_tab_kernel<<<128, blk, 0, stream>>>(rct, f1w, f1b, f2w, f2b, tab);

    // fused attention (writes into xs, which is free after pool_ln)
    attn_fused<<<NTOK * NHEADS / 4, blk, 0, stream>>>(
        qn, kvb, kvp, tab, rpi, qe, temp, sls, rpb, lt, lb, xs);

    // output projection
    gemm_bias<0><<<dim3(4, 392), blk, 0, stream>>>(xs, pw, pbi, out, NTOK, 256, 256);
}

// Round 2
// 688.640 us; speedup vs baseline: 1.6517x; 1.6517x over previous
//
#include <hip/hip_runtime.h>
#include <math.h>

#define NSEQ   3136      // N0 = 56*56
#define NTOK   25088     // B * NSEQ
#define BATCH  8
#define WID    56
#define NHEADS 8
#define HDIM   32
#define CDIM   256
#define PLEN   49
#define NEGC  -1000000000.0f

// attention tile constants
#define TJ     28        // pixels per block (half an image row)
#define NLOC   90        // 3 rows x 30 cols of local keys
#define NLT    9
#define KROWS  148       // 90 local + 49 pool + 9 learnable-token cols
#define VROWS  139       // 90 local + 49 pool
#define KPAD   36        // stride: 9 quads, odd -> conflict-minimal b128 reads
#define SW     68        // score row width (58 scores + 9 lt-dots, padded)
#define NES    67        // entries per pixel incl. lt pseudo-entries

__device__ __forceinline__ float gelu_exact(float x) {
    return 0.5f * x * (1.0f + erff(x * 0.70710678118654752440f));
}

// ---------------------------------------------------------------------------
// Tiled fp32 GEMM: C = A(MxK) @ B(KxN) + bias, optional exact-GELU epilogue.
// ---------------------------------------------------------------------------
template<int ACT>
__global__ __launch_bounds__(256) void gemm_bias(
    const float* __restrict__ A, const float* __restrict__ Bw,
    const float* __restrict__ bias, float* __restrict__ C,
    int M, int N, int K)
{
    __shared__ float As[16][68];
    __shared__ float Bs[16][68];
    const int tid = threadIdx.x;
    const int tx  = tid & 15, ty = tid >> 4;
    const int bm  = blockIdx.y * 64, bn = blockIdx.x * 64;
    float acc[4][4] = {};

    const int am  = tid >> 2;
    const int ak  = (tid & 3) * 4;
    const int bk  = tid >> 4;
    const int bn4 = (tid & 15) * 4;

    for (int k0 = 0; k0 < K; k0 += 16) {
        float4 av = make_float4(0.f, 0.f, 0.f, 0.f);
        if (bm + am < M)
            av = *reinterpret_cast<const float4*>(&A[(size_t)(bm + am) * K + k0 + ak]);
        As[ak+0][am] = av.x; As[ak+1][am] = av.y; As[ak+2][am] = av.z; As[ak+3][am] = av.w;

        float4 bv = *reinterpret_cast<const float4*>(&Bw[(size_t)(k0 + bk) * N + bn + bn4]);
        Bs[bk][bn4+0] = bv.x; Bs[bk][bn4+1] = bv.y; Bs[bk][bn4+2] = bv.z; Bs[bk][bn4+3] = bv.w;
        __syncthreads();

        #pragma unroll
        for (int kk = 0; kk < 16; kk++) {
            float a0 = As[kk][ty*4+0], a1 = As[kk][ty*4+1], a2 = As[kk][ty*4+2], a3 = As[kk][ty*4+3];
            float b0 = Bs[kk][tx*4+0], b1 = Bs[kk][tx*4+1], b2 = Bs[kk][tx*4+2], b3 = Bs[kk][tx*4+3];
            acc[0][0] += a0*b0; acc[0][1] += a0*b1; acc[0][2] += a0*b2; acc[0][3] += a0*b3;
            acc[1][0] += a1*b0; acc[1][1] += a1*b1; acc[1][2] += a1*b2; acc[1][3] += a1*b3;
            acc[2][0] += a2*b0; acc[2][1] += a2*b1; acc[2][2] += a2*b2; acc[2][3] += a2*b3;
            acc[3][0] += a3*b0; acc[3][1] += a3*b1; acc[3][2] += a3*b2; acc[3][3] += a3*b3;
        }
        __syncthreads();
    }

    const int n0 = bn + tx * 4;
    float4 bsv = *reinterpret_cast<const float4*>(&bias[n0]);
    #pragma unroll
    for (int r = 0; r < 4; r++) {
        int m = bm + ty * 4 + r;
        if (m < M) {
            float4 o;
            o.x = acc[r][0] + bsv.x;
            o.y = acc[r][1] + bsv.y;
            o.z = acc[r][2] + bsv.z;
            o.w = acc[r][3] + bsv.w;
            if (ACT == 1) {
                o.x = gelu_exact(o.x); o.y = gelu_exact(o.y);
                o.z = gelu_exact(o.z); o.w = gelu_exact(o.w);
            }
            *reinterpret_cast<float4*>(&C[(size_t)m * N + n0]) = o;
        }
    }
}

// ---------------------------------------------------------------------------
// In-place L2-normalize each 32-dim head group.
// ---------------------------------------------------------------------------
__global__ __launch_bounds__(256) void l2norm_groups(float* __restrict__ buf, int rowStride)
{
    size_t row = blockIdx.x;
    int c = threadIdx.x;
    size_t idx = row * (size_t)rowStride + c;
    float v = buf[idx];
    float ss = v * v;
    #pragma unroll
    for (int m = 16; m > 0; m >>= 1) ss += __shfl_xor(ss, m);
    float denom = fmaxf(sqrtf(ss), 1e-12f);
    buf[idx] = v / denom;
}

// ---------------------------------------------------------------------------
// 8x8 average pool of gelu'd sr output + LayerNorm. One block per (b, p).
// ---------------------------------------------------------------------------
__global__ __launch_bounds__(256) void pool_ln(
    const float* __restrict__ xs, const float* __restrict__ g,
    const float* __restrict__ bb, float* __restrict__ xp)
{
    int b = blockIdx.x / PLEN, p = blockIdx.x % PLEN;
    int ph = p / 7, pw = p % 7;
    int c = threadIdx.x;
    float s = 0.f;
    #pragma unroll
    for (int i = 0; i < 8; i++) {
        int rowpix = (ph * 8 + i) * WID + pw * 8;
        const float* base = &xs[((size_t)b * NSEQ + rowpix) * CDIM + c];
        #pragma unroll
        for (int jj = 0; jj < 8; jj++) s += base[(size_t)jj * CDIM];
    }
    s *= (1.f / 64.f);

    float ssum = s, ssq = s * s;
    #pragma unroll
    for (int m = 32; m > 0; m >>= 1) {
        ssum += __shfl_xor(ssum, m);
        ssq  += __shfl_xor(ssq, m);
    }
    __shared__ float r1[4], r2[4];
    int wv = threadIdx.x >> 6;
    if ((threadIdx.x & 63) == 0) { r1[wv] = ssum; r2[wv] = ssq; }
    __syncthreads();
    float tsum = r1[0] + r1[1] + r1[2] + r1[3];
    float tsq  = r2[0] + r2[1] + r2[2] + r2[3];
    float mu  = tsum * (1.f / 256.f);
    float var = tsq * (1.f / 256.f) - mu * mu;
    float o = (s - mu) * rsqrtf(var + 1e-5f) * g[c] + bb[c];
    xp[(size_t)blockIdx.x * CDIM + c] = o;
}

// ---------------------------------------------------------------------------
// CPB MLP table.
// ---------------------------------------------------------------------------
__global__ __launch_bounds__(256) void cpb_tab_kernel(
    const float* __restrict__ rct, const float* __restrict__ fc1w,
    const float* __restrict__ fc1b, const float* __restrict__ fc2w,
    const float* __restrict__ fc2b, float* __restrict__ tab)
{
    int gid = blockIdx.x * 256 + threadIdx.x;
    if (gid >= 4096 * 8) return;
    int t = gid >> 3, h = gid & 7;
    float c0 = rct[t * 2 + 0], c1 = rct[t * 2 + 1];
    float acc = 0.f;
    for (int i = 0; i < 512; i++) {
        float hid = fmaxf(c0 * fc1w[i] + c1 * fc1w[512 + i] + fc1b[i], 0.f);
        acc += hid * fc2w[i * 8 + h];
    }
    tab[t * 8 + h] = acc + fc2b[h];
}

// ---------------------------------------------------------------------------
// Tiled fused attention. One block per (b, h, image row, half-row):
// 28 pixels share 90 local keys (3 rows x 30 cols), 49 pooled keys, and the
// 9 learnable-token columns — all staged in LDS once. Entries per pixel:
//   e in [0,9): local window (bias rpb / NEG-masked)
//   e in [9,58): pooled (bias = tab[rpi] gather, prefetched to registers)
//   e in [58,67): learnable-token dots against q_norm (pseudo-entries)
// ---------------------------------------------------------------------------
__global__ __launch_bounds__(256) void attn_tile(
    const float* __restrict__ qn,   // (B,N,256)  L2-normalized q
    const float* __restrict__ kvb,  // (B,N,512)  [k normalized | v]
    const float* __restrict__ kvp,  // (B,49,512) [k_pool normalized | v_pool]
    const float* __restrict__ tab,  // (4096,8)
    const int*   __restrict__ rpi,  // (N*49)
    const float* __restrict__ qe,   // (8,32)
    const float* __restrict__ temp, // (8)
    const float* __restrict__ sls,  // (1)
    const float* __restrict__ rpb,  // (8,9)
    const float* __restrict__ lt,   // (8,32,9)
    const float* __restrict__ lb,   // (8,9)
    float* __restrict__ attout)     // (B,N,256)
{
    __shared__ float Ks[KROWS][KPAD];  // k local | k pool | lt columns
    __shared__ float Vs[VROWS][KPAD];  // v local (zeroed where invalid) | v pool
    __shared__ float Qs[TJ][KPAD];     // scaled q
    __shared__ float Qn[TJ][KPAD];     // normalized q (for lt dots)
    __shared__ float Ss[TJ][SW];       // scores -> attention weights

    const int tid  = threadIdx.x;
    const int bid  = blockIdx.x;
    const int half = bid & 1;
    const int rest = bid >> 1;
    const int i    = rest % WID;
    const int h    = (rest / WID) & 7;
    const int b    = rest / (WID * NHEADS);
    const int j0   = half * TJ;

    const float scale = log1pf(expf(temp[h])) * sls[0];

    // ---- stage q rows ----
    if (tid < TJ * 8) {
        int jl = tid >> 3, d4 = (tid & 7) * 4;
        int n  = i * WID + j0 + jl;
        float4 qv = *reinterpret_cast<const float4*>(&qn[((size_t)(b * NSEQ + n)) * CDIM + h * HDIM + d4]);
        float4 ev = *reinterpret_cast<const float4*>(&qe[h * HDIM + d4]);
        *reinterpret_cast<float4*>(&Qn[jl][d4]) = qv;
        float4 sv;
        sv.x = (qv.x + ev.x) * scale; sv.y = (qv.y + ev.y) * scale;
        sv.z = (qv.z + ev.z) * scale; sv.w = (qv.w + ev.w) * scale;
        *reinterpret_cast<float4*>(&Qs[jl][d4]) = sv;
    }
    // ---- stage local k/v (rows i-1..i+1, cols j0-1..j0+28) ----
    for (int idx = tid; idx < NLOC * 8; idx += 256) {
        int kk = idx >> 3, d4 = (idx & 7) * 4;
        int r = kk / 30, c = kk % 30;
        int gi = i - 1 + r, gj = j0 - 1 + c;
        bool vld = (gi >= 0) & (gi < WID) & (gj >= 0) & (gj < WID);
        int gic = min(max(gi, 0), WID - 1), gjc = min(max(gj, 0), WID - 1);
        const float* base = &kvb[((size_t)(b * NSEQ + gic * WID + gjc)) * 512 + h * HDIM];
        float4 k4 = *reinterpret_cast<const float4*>(base + d4);
        float4 v4 = *reinterpret_cast<const float4*>(base + 256 + d4);
        if (!vld) v4 = make_float4(0.f, 0.f, 0.f, 0.f);
        *reinterpret_cast<float4*>(&Ks[kk][d4]) = k4;
        *reinterpret_cast<float4*>(&Vs[kk][d4]) = v4;
    }
    // ---- stage pooled k/v ----
    for (int idx = tid; idx < PLEN * 8; idx += 256) {
        int kk = idx >> 3, d4 = (idx & 7) * 4;
        const float* base = &kvp[((size_t)(b * PLEN + kk)) * 512 + h * HDIM];
        *reinterpret_cast<float4*>(&Ks[NLOC + kk][d4]) = *reinterpret_cast<const float4*>(base + d4);
        *reinterpret_cast<float4*>(&Vs[NLOC + kk][d4]) = *reinterpret_cast<const float4*>(base + 256 + d4);
    }
    // ---- stage learnable-token columns ----
    for (int idx = tid; idx < NLT * HDIM; idx += 256) {
        int t = idx >> 5, d = idx & 31;
        Ks[NLOC + PLEN + t][d] = lt[(h * HDIM + d) * NLT + t];
    }
    // ---- prefetch biases into registers (overlaps staging latency) ----
    float bias[8];
    #pragma unroll
    for (int it = 0; it < 8; it++) {
        int s = tid + it * 256;
        bias[it] = 0.f;
        if (s < TJ * NES) {
            int jl = s / NES, e = s % NES;
            if (e < 9) {
                int gi = i - 1 + e / 3, gj = j0 + jl + (e % 3) - 1;
                bool vld = (gi >= 0) & (gi < WID) & (gj >= 0) & (gj < WID);
                bias[it] = vld ? rpb[h * 9 + e] : NEGC;
            } else if (e < 58) {
                int n = i * WID + j0 + jl;
                bias[it] = tab[rpi[(size_t)n * PLEN + (e - 9)] * 8 + h];
            } else {
                bias[it] = lb[h * 9 + (e - 58)];
            }
        }
    }
    __syncthreads();

    // ---- scores: thread <-> (pixel, entry) ----
    #pragma unroll
    for (int it = 0; it < 8; it++) {
        int s = tid + it * 256;
        if (s < TJ * NES) {
            int jl = s / NES, e = s % NES;
            const float* q = (e < 58) ? Qs[jl] : Qn[jl];
            int col;
            if (e < 9)       col = (e / 3) * 30 + jl + (e % 3);
            else if (e < 58) col = NLOC + (e - 9);
            else             col = NLOC + PLEN + (e - 58);
            float acc = bias[it];
            #pragma unroll
            for (int d4 = 0; d4 < 8; d4++) {
                float4 a = *reinterpret_cast<const float4*>(&q[d4 * 4]);
                float4 k4 = *reinterpret_cast<const float4*>(&Ks[col][d4 * 4]);
                acc += a.x * k4.x + a.y * k4.y + a.z * k4.z + a.w * k4.w;
            }
            Ss[jl][e] = acc;
        }
    }
    __syncthreads();

    // ---- softmax: wave <-> 7 pixels, lane <-> entry ----
    {
        int wv = tid >> 6, lane = tid & 63;
        for (int p = 0; p < 7; p++) {
            int jl = wv * 7 + p;
            float sc = (lane < 58) ? Ss[jl][lane] : -INFINITY;
            float mx = sc;
            #pragma unroll
            for (int m = 32; m > 0; m >>= 1) mx = fmaxf(mx, __shfl_xor(mx, m));
            float pe = (lane < 58) ? expf(sc - mx) : 0.f;
            float sum = pe;
            #pragma unroll
            for (int m = 32; m > 0; m >>= 1) sum += __shfl_xor(sum, m);
            float a = pe / sum;
            if (lane < 9) a += Ss[jl][58 + lane];   // post-softmax learnable add (incl. lb)
            if (lane < 58) Ss[jl][lane] = a;
        }
    }
    __syncthreads();

    // ---- output: thread <-> (pixel, dim4) ----
    if (tid < TJ * 8) {
        int jl = tid >> 3, dg = (tid & 7) * 4;
        float4 o = make_float4(0.f, 0.f, 0.f, 0.f);
        #pragma unroll
        for (int e = 0; e < 9; e++) {
            float a = Ss[jl][e];
            int col = (e / 3) * 30 + jl + (e % 3);
            float4 vv = *reinterpret_cast<const float4*>(&Vs[col][dg]);
            o.x += a * vv.x; o.y += a * vv.y; o.z += a * vv.z; o.w += a * vv.w;
        }
        for (int m = 0; m < PLEN; m++) {
            float a = Ss[jl][9 + m];
            float4 vv = *reinterpret_cast<const float4*>(&Vs[NLOC + m][dg]);
            o.x += a * vv.x; o.y += a * vv.y; o.z += a * vv.z; o.w += a * vv.w;
        }
        int n = i * WID + j0 + jl;
        *reinterpret_cast<float4*>(&attout[((size_t)(b * NSEQ + n)) * CDIM + h * HDIM + dg]) = o;
    }
}

// ---------------------------------------------------------------------------
// Workspace layout (floats): see round-1 comment. total 104.1 MB
// ---------------------------------------------------------------------------
extern "C" void kernel_launch(void* const* d_in, const int* in_sizes, int n_in,
                              void* d_out, int out_size, void* d_ws, size_t ws_size,
                              hipStream_t stream)
{
    const float* x    = (const float*)d_in[0];
    const float* sls  = (const float*)d_in[1];
    const float* rct  = (const float*)d_in[2];
    const float* q_w  = (const float*)d_in[3];
    const float* q_b  = (const float*)d_in[4];
    const float* qe   = (const float*)d_in[5];
    const float* temp = (const float*)d_in[6];
    const float* kv_w = (const float*)d_in[7];
    const float* kv_b = (const float*)d_in[8];
    const float* sr_w = (const float*)d_in[9];
    const float* sr_b = (const float*)d_in[10];
    const float* ng   = (const float*)d_in[11];
    const float* nb   = (const float*)d_in[12];
    const float* f1w  = (const float*)d_in[13];
    const float* f1b  = (const float*)d_in[14];
    const float* f2w  = (const float*)d_in[15];
    const float* f2b  = (const float*)d_in[16];
    const float* rpb  = (const float*)d_in[17];
    const float* lt   = (const float*)d_in[18];
    const float* lb   = (const float*)d_in[19];
    const float* pw   = (const float*)d_in[20];
    const float* pbi  = (const float*)d_in[21];
    const int*   rpi  = (const int*)d_in[22];

    if (ws_size < (size_t)26023936 * sizeof(float)) return;

    float* ws  = (float*)d_ws;
    float* qn  = ws;
    float* kvb = ws + 6422528;
    float* xs  = ws + 19267584;
    float* xp  = ws + 25690112;
    float* kvp = ws + 25790464;
    float* tab = ws + 25991168;
    float* out = (float*)d_out;

    dim3 blk(256);

    gemm_bias<0><<<dim3(4, 392), blk, 0, stream>>>(x, q_w, q_b, qn, NTOK, 256, 256);
    l2norm_groups<<<NTOK, blk, 0, stream>>>(qn, 256);

    gemm_bias<0><<<dim3(8, 392), blk, 0, stream>>>(x, kv_w, kv_b, kvb, NTOK, 512, 256);
    l2norm_groups<<<NTOK, blk, 0, stream>>>(kvb, 512);

    gemm_bias<1><<<dim3(4, 392), blk, 0, stream>>>(x, sr_w, sr_b, xs, NTOK, 256, 256);

    pool_ln<<<BATCH * PLEN, blk, 0, stream>>>(xs, ng, nb, xp);

    gemm_bias<0><<<dim3(8, 7), blk, 0, stream>>>(xp, kv_w, kv_b, kvp, BATCH * PLEN, 512, 256);
    l2norm_groups<<<BATCH * PLEN, blk, 0, stream>>>(kvp, 512);

    cpb_tab_kernel<<<128, blk, 0, stream>>>(rct, f1w, f1b, f2w, f2b, tab);

    // fused attention (writes into xs, free after pool_ln)
    attn_tile<<<BATCH * NHEADS * WID * 2, blk, 0, stream>>>(
        qn, kvb, kvp, tab, rpi, qe, temp, sls, rpb, lt, lb, xs);

    gemm_bias<0><<<dim3(4, 392), blk, 0, stream>>>(xs, pw, pbi, out, NTOK, 256, 256);
}

// Round 3
// 437.748 us; speedup vs baseline: 2.5983x; 1.5731x over previous
//
#include <hip/hip_runtime.h>
#include <math.h>

#define NSEQ   3136      // N0 = 56*56
#define NTOK   25088     // B * NSEQ
#define BATCH  8
#define WID    56
#define NHEADS 8
#define HDIM   32
#define CDIM   256
#define PLEN   49
#define NEGC  -1000000000.0f

// attention tile constants
#define TJ     28        // pixels per block (half an image row)
#define NLOC   90        // 3 rows x 30 cols of local keys

// XOR quad-swizzled LDS addressing, stride 32 floats (8 quads):
// float offset of quad d4 of column col
#define KQ(col, d4) (((col) << 5) + (((d4) ^ ((col) & 7)) << 2))

typedef __attribute__((ext_vector_type(8))) short short8;
typedef __attribute__((ext_vector_type(4))) float f32x4;

__device__ __forceinline__ float gelu_exact(float x) {
    return 0.5f * x * (1.0f + erff(x * 0.70710678118654752440f));
}

// round-to-nearest-even float -> bf16 (raw ushort)
__device__ __forceinline__ unsigned short f2bf(float f) {
    unsigned int u = __float_as_uint(f);
    u += 0x7fffu + ((u >> 16) & 1u);
    return (unsigned short)(u >> 16);
}

__device__ __forceinline__ void gl_lds16(const void* g, void* l) {
    __builtin_amdgcn_global_load_lds(
        (const __attribute__((address_space(1))) void*)g,
        (__attribute__((address_space(3))) void*)l, 16, 0, 0);
}

// ---------------------------------------------------------------------------
// bf16 MFMA GEMM (m97 structure): C = A(M x 256) @ Bt^T + bias, segmented
// epilogue. A, Bt are bf16 raw-ushort row-major with K=256 contiguous.
// Grid: (N/128, M/128), 256 threads (4 waves, 2x2 wave grid, 64x64 each).
// Segment by global n: [0,256)->o0(stride 256), [256,768)->o1(stride 512),
// [768,1024)->o2(stride 256, GELU). M must be a multiple of 128.
// ---------------------------------------------------------------------------
__global__ __launch_bounds__(256) void gemm_bt(
    const unsigned short* __restrict__ A,
    const unsigned short* __restrict__ Bt,
    const float* __restrict__ b0, const float* __restrict__ b1,
    const float* __restrict__ b2,
    float* __restrict__ o0, float* __restrict__ o1, float* __restrict__ o2)
{
    __shared__ short As[4096];   // 128 rows x 32 k (bf16)
    __shared__ short Bs[4096];
    const int tid = threadIdx.x;
    const int w = tid >> 6, lane = tid & 63;
    const int bm = blockIdx.y * 128;
    const int bn = blockIdx.x * 128;
    const int m0 = (w >> 1) * 64, n0 = (w & 1) * 64;
    const int lr = lane & 15, q8 = (lane >> 4) * 8, quad = lane >> 4;

    f32x4 acc[4][4] = {};

    const int srow = tid >> 2;
    const int scol = (tid & 3) * 8;           // halfword offset within 32-k row
    char* aB = (char*)As + w * 1024;
    char* bB = (char*)Bs + w * 1024;
    const unsigned short* Ap0 = A + (size_t)(bm + srow) * 256 + scol;
    const unsigned short* Ap1 = A + (size_t)(bm + srow + 64) * 256 + scol;
    const unsigned short* Bp0 = Bt + (size_t)(bn + srow) * 256 + scol;
    const unsigned short* Bp1 = Bt + (size_t)(bn + srow + 64) * 256 + scol;

    for (int k0 = 0; k0 < 256; k0 += 32) {
        if (k0) __syncthreads();
        gl_lds16(Ap0 + k0, aB);
        gl_lds16(Ap1 + k0, aB + 4096);
        gl_lds16(Bp0 + k0, bB);
        gl_lds16(Bp1 + k0, bB + 4096);
        __syncthreads();
        short8 af[4], bf[4];
        #pragma unroll
        for (int t = 0; t < 4; t++) {
            af[t] = *reinterpret_cast<const short8*>(&As[(m0 + t * 16 + lr) * 32 + q8]);
            bf[t] = *reinterpret_cast<const short8*>(&Bs[(n0 + t * 16 + lr) * 32 + q8]);
        }
        #pragma unroll
        for (int mt = 0; mt < 4; mt++)
            #pragma unroll
            for (int nt = 0; nt < 4; nt++)
                acc[mt][nt] = __builtin_amdgcn_mfma_f32_16x16x32_bf16(
                    af[mt], bf[nt], acc[mt][nt], 0, 0, 0);
    }

    // epilogue: segment select (wave-uniform: 128-wide n-tile within one segment)
    const float* bp; float* op; int ostr; int c0; bool act = false;
    if (bn < 256)      { bp = b0; op = o0; ostr = 256; c0 = bn; }
    else if (bn < 768) { bp = b1; op = o1; ostr = 512; c0 = bn - 256; }
    else               { bp = b2; op = o2; ostr = 256; c0 = bn - 768; act = true; }

    #pragma unroll
    for (int nt = 0; nt < 4; nt++) {
        int c = c0 + n0 + nt * 16 + lr;
        float bv = bp[c];
        #pragma unroll
        for (int mt = 0; mt < 4; mt++) {
            int m = bm + m0 + mt * 16 + quad * 4;
            #pragma unroll
            for (int r = 0; r < 4; r++) {
                float v = acc[mt][nt][r] + bv;
                if (act) v = gelu_exact(v);
                op[(size_t)(m + r) * ostr + c] = v;
            }
        }
    }
}

// ---------------------------------------------------------------------------
// fp32 -> bf16 convert, 4 elems/thread (x -> x_bf16)
// ---------------------------------------------------------------------------
__global__ __launch_bounds__(256) void convert_bf16(
    const float* __restrict__ in, unsigned short* __restrict__ outb, int n4)
{
    int i = blockIdx.x * 256 + threadIdx.x;
    if (i >= n4) return;
    float4 v = reinterpret_cast<const float4*>(in)[i];
    ushort4 u;
    u.x = f2bf(v.x); u.y = f2bf(v.y); u.z = f2bf(v.z); u.w = f2bf(v.w);
    reinterpret_cast<ushort4*>(outb)[i] = u;
}

// ---------------------------------------------------------------------------
// Transposed concat weight [q | kv | sr] -> wcat (1024 x 256 bf16)
// ---------------------------------------------------------------------------
__global__ __launch_bounds__(256) void prep_wcat(
    const float* __restrict__ qw, const float* __restrict__ kvw,
    const float* __restrict__ srw, unsigned short* __restrict__ wcat)
{
    int gid = blockIdx.x * 256 + threadIdx.x;   // 262144
    int n = gid >> 8, k = gid & 255;
    float v;
    if (n < 256)      v = qw[k * 256 + n];
    else if (n < 768) v = kvw[k * 512 + (n - 256)];
    else              v = srw[k * 256 + (n - 768)];
    wcat[gid] = f2bf(v);
}

__global__ __launch_bounds__(256) void prep_pwt(
    const float* __restrict__ pw, unsigned short* __restrict__ pwt)
{
    int gid = blockIdx.x * 256 + threadIdx.x;   // 65536
    int n = gid >> 8, k = gid & 255;
    pwt[gid] = f2bf(pw[k * 256 + n]);
}

// ---------------------------------------------------------------------------
// In-place L2-normalize each 32-dim head group (first 256 cols of each row).
// ---------------------------------------------------------------------------
__global__ __launch_bounds__(256) void l2norm_groups(float* __restrict__ buf, int rowStride)
{
    size_t row = blockIdx.x;
    int c = threadIdx.x;
    size_t idx = row * (size_t)rowStride + c;
    float v = buf[idx];
    float ss = v * v;
    #pragma unroll
    for (int m = 16; m > 0; m >>= 1) ss += __shfl_xor(ss, m);
    float denom = fmaxf(sqrtf(ss), 1e-12f);
    buf[idx] = v / denom;
}

// ---------------------------------------------------------------------------
// fp32 tiled GEMM (kept for the tiny pooled-kv projection, M=392)
// ---------------------------------------------------------------------------
template<int ACT>
__global__ __launch_bounds__(256) void gemm_bias(
    const float* __restrict__ A, const float* __restrict__ Bw,
    const float* __restrict__ bias, float* __restrict__ C,
    int M, int N, int K)
{
    __shared__ float Asm[16][68];
    __shared__ float Bsm[16][68];
    const int tid = threadIdx.x;
    const int tx  = tid & 15, ty = tid >> 4;
    const int bm  = blockIdx.y * 64, bn = blockIdx.x * 64;
    float acc[4][4] = {};

    const int am  = tid >> 2;
    const int ak  = (tid & 3) * 4;
    const int bk  = tid >> 4;
    const int bn4 = (tid & 15) * 4;

    for (int k0 = 0; k0 < K; k0 += 16) {
        float4 av = make_float4(0.f, 0.f, 0.f, 0.f);
        if (bm + am < M)
            av = *reinterpret_cast<const float4*>(&A[(size_t)(bm + am) * K + k0 + ak]);
        Asm[ak+0][am] = av.x; Asm[ak+1][am] = av.y; Asm[ak+2][am] = av.z; Asm[ak+3][am] = av.w;

        float4 bv = *reinterpret_cast<const float4*>(&Bw[(size_t)(k0 + bk) * N + bn + bn4]);
        Bsm[bk][bn4+0] = bv.x; Bsm[bk][bn4+1] = bv.y; Bsm[bk][bn4+2] = bv.z; Bsm[bk][bn4+3] = bv.w;
        __syncthreads();

        #pragma unroll
        for (int kk = 0; kk < 16; kk++) {
            float a0 = Asm[kk][ty*4+0], a1 = Asm[kk][ty*4+1], a2 = Asm[kk][ty*4+2], a3 = Asm[kk][ty*4+3];
            float b0 = Bsm[kk][tx*4+0], b1 = Bsm[kk][tx*4+1], b2 = Bsm[kk][tx*4+2], b3 = Bsm[kk][tx*4+3];
            acc[0][0] += a0*b0; acc[0][1] += a0*b1; acc[0][2] += a0*b2; acc[0][3] += a0*b3;
            acc[1][0] += a1*b0; acc[1][1] += a1*b1; acc[1][2] += a1*b2; acc[1][3] += a1*b3;
            acc[2][0] += a2*b0; acc[2][1] += a2*b1; acc[2][2] += a2*b2; acc[2][3] += a2*b3;
            acc[3][0] += a3*b0; acc[3][1] += a3*b1; acc[3][2] += a3*b2; acc[3][3] += a3*b3;
        }
        __syncthreads();
    }

    const int n0 = bn + tx * 4;
    float4 bsv = *reinterpret_cast<const float4*>(&bias[n0]);
    #pragma unroll
    for (int r = 0; r < 4; r++) {
        int m = bm + ty * 4 + r;
        if (m < M) {
            float4 o;
            o.x = acc[r][0] + bsv.x;
            o.y = acc[r][1] + bsv.y;
            o.z = acc[r][2] + bsv.z;
            o.w = acc[r][3] + bsv.w;
            if (ACT == 1) {
                o.x = gelu_exact(o.x); o.y = gelu_exact(o.y);
                o.z = gelu_exact(o.z); o.w = gelu_exact(o.w);
            }
            *reinterpret_cast<float4*>(&C[(size_t)m * N + n0]) = o;
        }
    }
}

// ---------------------------------------------------------------------------
// 8x8 average pool of gelu'd sr output + LayerNorm. One block per (b, p).
// ---------------------------------------------------------------------------
__global__ __launch_bounds__(256) void pool_ln(
    const float* __restrict__ xs, const float* __restrict__ g,
    const float* __restrict__ bb, float* __restrict__ xp)
{
    int b = blockIdx.x / PLEN, p = blockIdx.x % PLEN;
    int ph = p / 7, pw = p % 7;
    int c = threadIdx.x;
    float s = 0.f;
    #pragma unroll
    for (int i = 0; i < 8; i++) {
        int rowpix = (ph * 8 + i) * WID + pw * 8;
        const float* base = &xs[((size_t)b * NSEQ + rowpix) * CDIM + c];
        #pragma unroll
        for (int jj = 0; jj < 8; jj++) s += base[(size_t)jj * CDIM];
    }
    s *= (1.f / 64.f);

    float ssum = s, ssq = s * s;
    #pragma unroll
    for (int m = 32; m > 0; m >>= 1) {
        ssum += __shfl_xor(ssum, m);
        ssq  += __shfl_xor(ssq, m);
    }
    __shared__ float r1[4], r2[4];
    int wv = threadIdx.x >> 6;
    if ((threadIdx.x & 63) == 0) { r1[wv] = ssum; r2[wv] = ssq; }
    __syncthreads();
    float tsum = r1[0] + r1[1] + r1[2] + r1[3];
    float tsq  = r2[0] + r2[1] + r2[2] + r2[3];
    float mu  = tsum * (1.f / 256.f);
    float var = tsq * (1.f / 256.f) - mu * mu;
    float o = (s - mu) * rsqrtf(var + 1e-5f) * g[c] + bb[c];
    xp[(size_t)blockIdx.x * CDIM + c] = o;
}

// ---------------------------------------------------------------------------
// CPB MLP table.
// ---------------------------------------------------------------------------
__global__ __launch_bounds__(256) void cpb_tab_kernel(
    const float* __restrict__ rct, const float* __restrict__ fc1w,
    const float* __restrict__ fc1b, const float* __restrict__ fc2w,
    const float* __restrict__ fc2b, float* __restrict__ tab)
{
    int gid = blockIdx.x * 256 + threadIdx.x;
    if (gid >= 4096 * 8) return;
    int t = gid >> 3, h = gid & 7;
    float c0 = rct[t * 2 + 0], c1 = rct[t * 2 + 1];
    float acc = 0.f;
    for (int i = 0; i < 512; i++) {
        float hid = fmaxf(c0 * fc1w[i] + c1 * fc1w[512 + i] + fc1b[i], 0.f);
        acc += hid * fc2w[i * 8 + h];
    }
    tab[t * 8 + h] = acc + fc2b[h];
}

// ---------------------------------------------------------------------------
// Tiled fused attention (swizzled LDS, 46.9 KB -> 3 blocks/CU).
// Entries per pixel: [0,9) local, [9,58) pooled, [58,67) learnable-token
// pseudo-entries computed with scaled Q and corrected post-softmax by
// corr[e] = lb - qe.lt (so the Qn buffer is not needed).
// Output written as bf16 (raw ushort) for the MFMA proj GEMM.
// ---------------------------------------------------------------------------
__global__ __launch_bounds__(256) void attn_tile(
    const float* __restrict__ qn,   // (B,N,256)  L2-normalized q
    const float* __restrict__ kvb,  // (B,N,512)  [k normalized | v]
    const float* __restrict__ kvp,  // (B,49,512) [k_pool normalized | v_pool]
    const float* __restrict__ tab,  // (4096,8)
    const int*   __restrict__ rpi,  // (N*49)
    const float* __restrict__ qe,   // (8,32)
    const float* __restrict__ temp, // (8)
    const float* __restrict__ sls,  // (1)
    const float* __restrict__ rpb,  // (8,9)
    const float* __restrict__ lt,   // (8,32,9)
    const float* __restrict__ lb,   // (8,9)
    unsigned short* __restrict__ ab)// (B,N,256) bf16 out
{
    __shared__ float Ks[148 * 32];  // local 0..89 | pool 90..138 | lt 139..147
    __shared__ float Vs[139 * 32];  // local (zeroed where invalid) | pool
    __shared__ float Qs[28 * 32];   // scaled q
    __shared__ float Ss[28][68];    // scores -> weights (+ raw lt dots at 58..66)
    __shared__ float corr[12];

    const int tid  = threadIdx.x;
    const int bid  = blockIdx.x;
    const int half = bid & 1;
    const int rest = bid >> 1;
    const int i    = rest % WID;
    const int h    = (rest / WID) & 7;
    const int b    = rest / (WID * NHEADS);
    const int j0   = half * TJ;

    const float scale = log1pf(expf(temp[h])) * sls[0];
    const float inv = 1.0f / scale;

    // lt post-softmax correction: lb - qe.lt
    if (tid < 9) {
        float s = 0.f;
        for (int d = 0; d < 32; d++) s += qe[h * 32 + d] * lt[(h * 32 + d) * 9 + tid];
        corr[tid] = lb[h * 9 + tid] - s;
    }
    // stage scaled q
    if (tid < 224) {
        int jl = tid >> 3, d4 = (tid & 7) * 4;
        int n  = i * WID + j0 + jl;
        float4 qv = *reinterpret_cast<const float4*>(&qn[((size_t)(b * NSEQ + n)) * CDIM + h * HDIM + d4]);
        float4 ev = *reinterpret_cast<const float4*>(&qe[h * HDIM + d4]);
        float4 sv;
        sv.x = (qv.x + ev.x) * scale; sv.y = (qv.y + ev.y) * scale;
        sv.z = (qv.z + ev.z) * scale; sv.w = (qv.w + ev.w) * scale;
        *reinterpret_cast<float4*>(&Qs[(tid >> 3) * 32 + d4]) = sv;
    }
    // stage local k/v (swizzled)
    for (int idx = tid; idx < NLOC * 8; idx += 256) {
        int kk = idx >> 3, d4 = idx & 7;
        int r = kk / 30, c = kk % 30;
        int gi = i - 1 + r, gj = j0 - 1 + c;
        bool vld = (gi >= 0) & (gi < WID) & (gj >= 0) & (gj < WID);
        int gic = min(max(gi, 0), WID - 1), gjc = min(max(gj, 0), WID - 1);
        const float* base = &kvb[((size_t)(b * NSEQ + gic * WID + gjc)) * 512 + h * HDIM];
        float4 k4 = *reinterpret_cast<const float4*>(base + d4 * 4);
        float4 v4 = *reinterpret_cast<const float4*>(base + 256 + d4 * 4);
        if (!vld) v4 = make_float4(0.f, 0.f, 0.f, 0.f);
        int off = KQ(kk, d4);
        *reinterpret_cast<float4*>(&Ks[off]) = k4;
        *reinterpret_cast<float4*>(&Vs[off]) = v4;
    }
    // stage pooled k/v
    for (int idx = tid; idx < PLEN * 8; idx += 256) {
        int kk = idx >> 3, d4 = idx & 7;
        const float* base = &kvp[((size_t)(b * PLEN + kk)) * 512 + h * HDIM];
        int off = KQ(NLOC + kk, d4);
        *reinterpret_cast<float4*>(&Ks[off]) = *reinterpret_cast<const float4*>(base + d4 * 4);
        *reinterpret_cast<float4*>(&Vs[off]) = *reinterpret_cast<const float4*>(base + 256 + d4 * 4);
    }
    // stage learnable-token columns
    for (int idx = tid; idx < 9 * HDIM; idx += 256) {
        int t = idx >> 5, d = idx & 31;
        Ks[KQ(139 + t, d >> 2) + (d & 3)] = lt[(h * HDIM + d) * 9 + t];
    }
    // prefetch biases (overlaps staging latency)
    float bias[8];
    #pragma unroll
    for (int it = 0; it < 8; it++) {
        int s = tid + it * 256;
        bias[it] = 0.f;
        if (s < TJ * 67) {
            int jl = s / 67, e = s % 67;
            if (e < 9) {
                int gi = i - 1 + e / 3, gj = j0 + jl + (e % 3) - 1;
                bool vld = (gi >= 0) & (gi < WID) & (gj >= 0) & (gj < WID);
                bias[it] = vld ? rpb[h * 9 + e] : NEGC;
            } else if (e < 58) {
                int n = i * WID + j0 + jl;
                bias[it] = tab[rpi[(size_t)n * PLEN + (e - 9)] * 8 + h];
            }
        }
    }
    __syncthreads();

    // scores: thread <-> (pixel, entry)
    #pragma unroll
    for (int it = 0; it < 8; it++) {
        int s = tid + it * 256;
        if (s < TJ * 67) {
            int jl = s / 67, e = s % 67;
            int col = (e < 9)  ? (e / 3) * 30 + jl + (e % 3)
                    : (e < 58) ? NLOC + (e - 9)
                               : 139 + (e - 58);
            const float* q = &Qs[jl * 32];
            float a = bias[it];
            #pragma unroll
            for (int d4 = 0; d4 < 8; d4++) {
                float4 qv = *reinterpret_cast<const float4*>(&q[d4 * 4]);
                float4 k4 = *reinterpret_cast<const float4*>(&Ks[KQ(col, d4)]);
                a += qv.x * k4.x + qv.y * k4.y + qv.z * k4.z + qv.w * k4.w;
            }
            Ss[jl][e] = a;
        }
    }
    __syncthreads();

    // softmax: wave <-> 7 pixels, lane <-> entry
    {
        int wv = tid >> 6, lane = tid & 63;
        for (int p = 0; p < 7; p++) {
            int jl = wv * 7 + p;
            float sc = (lane < 58) ? Ss[jl][lane] : -INFINITY;
            float mx = sc;
            #pragma unroll
            for (int m = 32; m > 0; m >>= 1) mx = fmaxf(mx, __shfl_xor(mx, m));
            float pe = (lane < 58) ? expf(sc - mx) : 0.f;
            float sum = pe;
            #pragma unroll
            for (int m = 32; m > 0; m >>= 1) sum += __shfl_xor(sum, m);
            float a = pe / sum;
            if (lane < 9) a += Ss[jl][58 + lane] * inv + corr[lane];
            if (lane < 58) Ss[jl][lane] = a;
        }
    }
    __syncthreads();

    // output: thread <-> (pixel, dim4), bf16 write
    if (tid < 224) {
        int jl = tid >> 3, d4 = tid & 7;
        float4 o = make_float4(0.f, 0.f, 0.f, 0.f);
        #pragma unroll
        for (int e = 0; e < 9; e++) {
            float a = Ss[jl][e];
            int col = (e / 3) * 30 + jl + (e % 3);
            float4 vv = *reinterpret_cast<const float4*>(&Vs[KQ(col, d4)]);
            o.x += a * vv.x; o.y += a * vv.y; o.z += a * vv.z; o.w += a * vv.w;
        }
        for (int m = 0; m < PLEN; m++) {
            float a = Ss[jl][9 + m];
            float4 vv = *reinterpret_cast<const float4*>(&Vs[KQ(NLOC + m, d4)]);
            o.x += a * vv.x; o.y += a * vv.y; o.z += a * vv.z; o.w += a * vv.w;
        }
        int n = i * WID + j0 + jl;
        ushort4 u;
        u.x = f2bf(o.x); u.y = f2bf(o.y); u.z = f2bf(o.z); u.w = f2bf(o.w);
        *reinterpret_cast<ushort4*>(&ab[((size_t)(b * NSEQ + n)) * CDIM + h * HDIM + d4 * 4]) = u;
    }
}

// ---------------------------------------------------------------------------
// Workspace (floats), total 26,023,936 = 104.1 MB (same bound as round 1/2):
//   qn    @ 0         : 6,422,528   (B,N,256)
//   kvbuf @ 6422528   : 12,845,056  (B,N,512)
//   xs    @ 19267584  : 6,422,528   (B,N,256) gelu(sr);
//                       after pool_ln: ab(bf16) @ xs[0:3211264],
//                                      pwt(bf16) @ xs[3211264:3244032]
//   xp    @ 25690112  : 100,352
//   kvp   @ 25790464  : 200,704
//   tab   @ 25991168  : 32,768
// d_out used as scratch until proj overwrites it:
//   xbf  (bf16 x, 6,422,528 elems) @ d_out[0:3211264]
//   wcat (bf16 1024x256)           @ d_out[3211264:3342336]
// ---------------------------------------------------------------------------
extern "C" void kernel_launch(void* const* d_in, const int* in_sizes, int n_in,
                              void* d_out, int out_size, void* d_ws, size_t ws_size,
                              hipStream_t stream)
{
    const float* x    = (const float*)d_in[0];
    const float* sls  = (const float*)d_in[1];
    const float* rct  = (const float*)d_in[2];
    const float* q_w  = (const float*)d_in[3];
    const float* q_b  = (const float*)d_in[4];
    const float* qe   = (const float*)d_in[5];
    const float* temp = (const float*)d_in[6];
    const float* kv_w = (const float*)d_in[7];
    const float* kv_b = (const float*)d_in[8];
    const float* sr_w = (const float*)d_in[9];
    const float* sr_b = (const float*)d_in[10];
    const float* ng   = (const float*)d_in[11];
    const float* nb   = (const float*)d_in[12];
    const float* f1w  = (const float*)d_in[13];
    const float* f1b  = (const float*)d_in[14];
    const float* f2w  = (const float*)d_in[15];
    const float* f2b  = (const float*)d_in[16];
    const float* rpb  = (const float*)d_in[17];
    const float* lt   = (const float*)d_in[18];
    const float* lb   = (const float*)d_in[19];
    const float* pw   = (const float*)d_in[20];
    const float* pbi  = (const float*)d_in[21];
    const int*   rpi  = (const int*)d_in[22];

    if (ws_size < (size_t)26023936 * sizeof(float)) return;

    float* ws  = (float*)d_ws;
    float* qn  = ws;
    float* kvbuf = ws + 6422528;
    float* xs  = ws + 19267584;
    float* xp  = ws + 25690112;
    float* kvp = ws + 25790464;
    float* tab = ws + 25991168;
    float* out = (float*)d_out;

    unsigned short* ab   = (unsigned short*)xs;                  // bf16 attn out
    unsigned short* pwt  = (unsigned short*)(xs + 3211264);      // bf16 proj w^T
    unsigned short* xbf  = (unsigned short*)out;                 // bf16 x
    unsigned short* wcat = (unsigned short*)(out + 3211264);     // bf16 [q|kv|sr]^T

    dim3 blk(256);

    // prep: x -> bf16 (in d_out scratch), concat weight transpose
    convert_bf16<<<6272, blk, 0, stream>>>(x, xbf, 1605632);
    prep_wcat<<<1024, blk, 0, stream>>>(q_w, kv_w, sr_w, wcat);

    // fused q|kv|sr MFMA GEMM: outputs qn, kvbuf, xs(gelu)
    gemm_bt<<<dim3(8, 196), blk, 0, stream>>>(xbf, wcat, q_b, kv_b, sr_b,
                                              qn, kvbuf, xs);

    l2norm_groups<<<NTOK, blk, 0, stream>>>(qn, 256);
    l2norm_groups<<<NTOK, blk, 0, stream>>>(kvbuf, 512);

    pool_ln<<<BATCH * PLEN, blk, 0, stream>>>(xs, ng, nb, xp);

    // proj weight transpose (into xs scratch — xs is dead after pool_ln)
    prep_pwt<<<256, blk, 0, stream>>>(pw, pwt);

    // pooled kv projection (tiny, fp32 path) + normalize k half
    gemm_bias<0><<<dim3(8, 7), blk, 0, stream>>>(xp, kv_w, kv_b, kvp, BATCH * PLEN, 512, 256);
    l2norm_groups<<<BATCH * PLEN, blk, 0, stream>>>(kvp, 512);

    cpb_tab_kernel<<<128, blk, 0, stream>>>(rct, f1w, f1b, f2w, f2b, tab);

    // fused attention -> bf16 ab
    attn_tile<<<BATCH * NHEADS * WID * 2, blk, 0, stream>>>(
        qn, kvbuf, kvp, tab, rpi, qe, temp, sls, rpb, lt, lb, ab);

    // output projection (MFMA): grid.x=2 -> segment-0 path, out fp32
    gemm_bt<<<dim3(2, 196), blk, 0, stream>>>(ab, pwt, pbi, pbi, pbi,
                                              out, out, out);
}

// Round 4
// 378.712 us; speedup vs baseline: 3.0033x; 1.1559x over previous
//
#include <hip/hip_runtime.h>
#include <math.h>

#define NSEQ   3136      // N0 = 56*56
#define NTOK   25088     // B * NSEQ
#define BATCH  8
#define WID    56
#define NHEADS 8
#define HDIM   32
#define CDIM   256
#define PLEN   49
#define NEGC  -1000000000.0f

#define TJ     28        // pixels per block (half an image row)
#define NLOC   90        // 3 rows x 30 cols of local keys

typedef __attribute__((ext_vector_type(8))) short short8;
typedef __attribute__((ext_vector_type(4))) float f32x4;
typedef __attribute__((ext_vector_type(8))) _Float16 half8;
typedef __attribute__((ext_vector_type(4))) _Float16 half4_t;

__device__ __forceinline__ float gelu_exact(float x) {
    return 0.5f * x * (1.0f + erff(x * 0.70710678118654752440f));
}

__device__ __forceinline__ unsigned short f2bf(float f) {
    unsigned int u = __float_as_uint(f);
    u += 0x7fffu + ((u >> 16) & 1u);
    return (unsigned short)(u >> 16);
}

__device__ __forceinline__ void gl_lds16(const void* g, void* l) {
    __builtin_amdgcn_global_load_lds(
        (const __attribute__((address_space(1))) void*)g,
        (__attribute__((address_space(3))) void*)l, 16, 0, 0);
}

// ---------------------------------------------------------------------------
// bf16 MFMA GEMM (m97 structure), segmented epilogue. (unchanged from R3)
// ---------------------------------------------------------------------------
__global__ __launch_bounds__(256) void gemm_bt(
    const unsigned short* __restrict__ A,
    const unsigned short* __restrict__ Bt,
    const float* __restrict__ b0, const float* __restrict__ b1,
    const float* __restrict__ b2,
    float* __restrict__ o0, float* __restrict__ o1, float* __restrict__ o2)
{
    __shared__ short As[4096];
    __shared__ short Bs[4096];
    const int tid = threadIdx.x;
    const int w = tid >> 6, lane = tid & 63;
    const int bm = blockIdx.y * 128;
    const int bn = blockIdx.x * 128;
    const int m0 = (w >> 1) * 64, n0 = (w & 1) * 64;
    const int lr = lane & 15, q8 = (lane >> 4) * 8, quad = lane >> 4;

    f32x4 acc[4][4] = {};

    const int srow = tid >> 2;
    const int scol = (tid & 3) * 8;
    char* aB = (char*)As + w * 1024;
    char* bB = (char*)Bs + w * 1024;
    const unsigned short* Ap0 = A + (size_t)(bm + srow) * 256 + scol;
    const unsigned short* Ap1 = A + (size_t)(bm + srow + 64) * 256 + scol;
    const unsigned short* Bp0 = Bt + (size_t)(bn + srow) * 256 + scol;
    const unsigned short* Bp1 = Bt + (size_t)(bn + srow + 64) * 256 + scol;

    for (int k0 = 0; k0 < 256; k0 += 32) {
        if (k0) __syncthreads();
        gl_lds16(Ap0 + k0, aB);
        gl_lds16(Ap1 + k0, aB + 4096);
        gl_lds16(Bp0 + k0, bB);
        gl_lds16(Bp1 + k0, bB + 4096);
        __syncthreads();
        short8 af[4], bf[4];
        #pragma unroll
        for (int t = 0; t < 4; t++) {
            af[t] = *reinterpret_cast<const short8*>(&As[(m0 + t * 16 + lr) * 32 + q8]);
            bf[t] = *reinterpret_cast<const short8*>(&Bs[(n0 + t * 16 + lr) * 32 + q8]);
        }
        #pragma unroll
        for (int mt = 0; mt < 4; mt++)
            #pragma unroll
            for (int nt = 0; nt < 4; nt++)
                acc[mt][nt] = __builtin_amdgcn_mfma_f32_16x16x32_bf16(
                    af[mt], bf[nt], acc[mt][nt], 0, 0, 0);
    }

    const float* bp; float* op; int ostr; int c0; bool act = false;
    if (bn < 256)      { bp = b0; op = o0; ostr = 256; c0 = bn; }
    else if (bn < 768) { bp = b1; op = o1; ostr = 512; c0 = bn - 256; }
    else               { bp = b2; op = o2; ostr = 256; c0 = bn - 768; act = true; }

    #pragma unroll
    for (int nt = 0; nt < 4; nt++) {
        int c = c0 + n0 + nt * 16 + lr;
        float bv = bp[c];
        #pragma unroll
        for (int mt = 0; mt < 4; mt++) {
            int m = bm + m0 + mt * 16 + quad * 4;
            #pragma unroll
            for (int r = 0; r < 4; r++) {
                float v = acc[mt][nt][r] + bv;
                if (act) v = gelu_exact(v);
                op[(size_t)(m + r) * ostr + c] = v;
            }
        }
    }
}

// ---------------------------------------------------------------------------
// Merged prep: [0,6272) x->bf16 | [6272,7296) wcat | [7296,7424) cpb table
// ---------------------------------------------------------------------------
__global__ __launch_bounds__(256) void prep_misc(
    const float* __restrict__ x, unsigned short* __restrict__ xbf,
    const float* __restrict__ qw, const float* __restrict__ kvw,
    const float* __restrict__ srw, unsigned short* __restrict__ wcat,
    const float* __restrict__ rct, const float* __restrict__ fc1w,
    const float* __restrict__ fc1b, const float* __restrict__ fc2w,
    const float* __restrict__ fc2b, float* __restrict__ tab)
{
    int bid = blockIdx.x, tid = threadIdx.x;
    if (bid < 6272) {
        int i = bid * 256 + tid;
        float4 v = reinterpret_cast<const float4*>(x)[i];
        ushort4 u;
        u.x = f2bf(v.x); u.y = f2bf(v.y); u.z = f2bf(v.z); u.w = f2bf(v.w);
        reinterpret_cast<ushort4*>(xbf)[i] = u;
    } else if (bid < 7296) {
        int gid = (bid - 6272) * 256 + tid;
        int n = gid >> 8, k = gid & 255;
        float v;
        if (n < 256)      v = qw[k * 256 + n];
        else if (n < 768) v = kvw[k * 512 + (n - 256)];
        else              v = srw[k * 256 + (n - 768)];
        wcat[gid] = f2bf(v);
    } else {
        int gid = (bid - 7296) * 256 + tid;
        if (gid >= 4096 * 8) return;
        int t = gid >> 3, h = gid & 7;
        float c0 = rct[t * 2 + 0], c1 = rct[t * 2 + 1];
        float acc = 0.f;
        for (int i = 0; i < 512; i++) {
            float hid = fmaxf(c0 * fc1w[i] + c1 * fc1w[512 + i] + fc1b[i], 0.f);
            acc += hid * fc2w[i * 8 + h];
        }
        tab[t * 8 + h] = acc + fc2b[h];
    }
}

// ---------------------------------------------------------------------------
// Fused L2-norm for qn (stride 256) and kvbuf k-half (stride 512), one launch.
// ---------------------------------------------------------------------------
__global__ __launch_bounds__(256) void l2norm_both(
    float* __restrict__ qn, float* __restrict__ kvbuf)
{
    int r = blockIdx.x;
    size_t idx = (r < NTOK) ? ((size_t)r * 256 + threadIdx.x)
                            : ((size_t)(r - NTOK) * 512 + threadIdx.x);
    float* buf = (r < NTOK) ? qn : kvbuf;
    float v = buf[idx];
    float ss = v * v;
    #pragma unroll
    for (int m = 16; m > 0; m >>= 1) ss += __shfl_xor(ss, m);
    buf[idx] = v / fmaxf(sqrtf(ss), 1e-12f);
}

// ---------------------------------------------------------------------------
// pool+LN (blocks 0..391) fused with proj-weight transpose (blocks 392..647)
// ---------------------------------------------------------------------------
__global__ __launch_bounds__(256) void pool_ln_pwt(
    const float* __restrict__ xs, const float* __restrict__ g,
    const float* __restrict__ bb, float* __restrict__ xp,
    const float* __restrict__ pw, unsigned short* __restrict__ pwt)
{
    if (blockIdx.x >= BATCH * PLEN) {
        int gid = (blockIdx.x - BATCH * PLEN) * 256 + threadIdx.x;
        int n = gid >> 8, k = gid & 255;
        pwt[gid] = f2bf(pw[k * 256 + n]);
        return;
    }
    int b = blockIdx.x / PLEN, p = blockIdx.x % PLEN;
    int ph = p / 7, pw_ = p % 7;
    int c = threadIdx.x;
    float s = 0.f;
    #pragma unroll
    for (int i = 0; i < 8; i++) {
        int rowpix = (ph * 8 + i) * WID + pw_ * 8;
        const float* base = &xs[((size_t)b * NSEQ + rowpix) * CDIM + c];
        #pragma unroll
        for (int jj = 0; jj < 8; jj++) s += base[(size_t)jj * CDIM];
    }
    s *= (1.f / 64.f);

    float ssum = s, ssq = s * s;
    #pragma unroll
    for (int m = 32; m > 0; m >>= 1) {
        ssum += __shfl_xor(ssum, m);
        ssq  += __shfl_xor(ssq, m);
    }
    __shared__ float r1[4], r2[4];
    int wv = threadIdx.x >> 6;
    if ((threadIdx.x & 63) == 0) { r1[wv] = ssum; r2[wv] = ssq; }
    __syncthreads();
    float tsum = r1[0] + r1[1] + r1[2] + r1[3];
    float tsq  = r2[0] + r2[1] + r2[2] + r2[3];
    float mu  = tsum * (1.f / 256.f);
    float var = tsq * (1.f / 256.f) - mu * mu;
    float o = (s - mu) * rsqrtf(var + 1e-5f) * g[c] + bb[c];
    xp[(size_t)blockIdx.x * CDIM + c] = o;
}

// ---------------------------------------------------------------------------
// fp32 tiled GEMM (tiny pooled-kv projection, M=392). (unchanged)
// ---------------------------------------------------------------------------
template<int ACT>
__global__ __launch_bounds__(256) void gemm_bias(
    const float* __restrict__ A, const float* __restrict__ Bw,
    const float* __restrict__ bias, float* __restrict__ C,
    int M, int N, int K)
{
    __shared__ float Asm[16][68];
    __shared__ float Bsm[16][68];
    const int tid = threadIdx.x;
    const int tx  = tid & 15, ty = tid >> 4;
    const int bm  = blockIdx.y * 64, bn = blockIdx.x * 64;
    float acc[4][4] = {};

    const int am  = tid >> 2;
    const int ak  = (tid & 3) * 4;
    const int bk  = tid >> 4;
    const int bn4 = (tid & 15) * 4;

    for (int k0 = 0; k0 < K; k0 += 16) {
        float4 av = make_float4(0.f, 0.f, 0.f, 0.f);
        if (bm + am < M)
            av = *reinterpret_cast<const float4*>(&A[(size_t)(bm + am) * K + k0 + ak]);
        Asm[ak+0][am] = av.x; Asm[ak+1][am] = av.y; Asm[ak+2][am] = av.z; Asm[ak+3][am] = av.w;

        float4 bv = *reinterpret_cast<const float4*>(&Bw[(size_t)(k0 + bk) * N + bn + bn4]);
        Bsm[bk][bn4+0] = bv.x; Bsm[bk][bn4+1] = bv.y; Bsm[bk][bn4+2] = bv.z; Bsm[bk][bn4+3] = bv.w;
        __syncthreads();

        #pragma unroll
        for (int kk = 0; kk < 16; kk++) {
            float a0 = Asm[kk][ty*4+0], a1 = Asm[kk][ty*4+1], a2 = Asm[kk][ty*4+2], a3 = Asm[kk][ty*4+3];
            float b0 = Bsm[kk][tx*4+0], b1 = Bsm[kk][tx*4+1], b2 = Bsm[kk][tx*4+2], b3 = Bsm[kk][tx*4+3];
            acc[0][0] += a0*b0; acc[0][1] += a0*b1; acc[0][2] += a0*b2; acc[0][3] += a0*b3;
            acc[1][0] += a1*b0; acc[1][1] += a1*b1; acc[1][2] += a1*b2; acc[1][3] += a1*b3;
            acc[2][0] += a2*b0; acc[2][1] += a2*b1; acc[2][2] += a2*b2; acc[2][3] += a2*b3;
            acc[3][0] += a3*b0; acc[3][1] += a3*b1; acc[3][2] += a3*b2; acc[3][3] += a3*b3;
        }
        __syncthreads();
    }

    const int n0 = bn + tx * 4;
    float4 bsv = *reinterpret_cast<const float4*>(&bias[n0]);
    #pragma unroll
    for (int r = 0; r < 4; r++) {
        int m = bm + ty * 4 + r;
        if (m < M) {
            float4 o;
            o.x = acc[r][0] + bsv.x;
            o.y = acc[r][1] + bsv.y;
            o.z = acc[r][2] + bsv.z;
            o.w = acc[r][3] + bsv.w;
            if (ACT == 1) {
                o.x = gelu_exact(o.x); o.y = gelu_exact(o.y);
                o.z = gelu_exact(o.z); o.w = gelu_exact(o.w);
            }
            *reinterpret_cast<float4*>(&C[(size_t)m * N + n0]) = o;
        }
    }
}

// ---------------------------------------------------------------------------
// MFMA-based fused attention. Block = (b, h, row, half): 28 pixels.
// Pool+lt scores via mfma_f32_16x16x32_f16 (q split hi/lo, k single fp16);
// pool AV via mfma (a fp16, v fp16). Local (9 entries) stays scalar fp32.
// kvp k-half normalized during staging (saves a kernel).
// LDS ~42.7 KB with phase-aliased regions -> 3 blocks/CU.
// ---------------------------------------------------------------------------
__global__ __launch_bounds__(256) void attn_tile(
    const float* __restrict__ qn,   // (B,N,256)  L2-normalized q
    const float* __restrict__ kvb,  // (B,N,512)  [k normalized | v]
    const float* __restrict__ kvp,  // (B,49,512) [k_pool UNnormalized | v_pool]
    const float* __restrict__ tab,  // (4096,8)
    const int*   __restrict__ rpi,  // (N*49)
    const float* __restrict__ qe,   // (8,32)
    const float* __restrict__ temp, // (8)
    const float* __restrict__ sls,  // (1)
    const float* __restrict__ rpb,  // (8,9)
    const float* __restrict__ lt,   // (8,32,9)
    const float* __restrict__ lb,   // (8,9)
    unsigned short* __restrict__ ab)// (B,N,256) bf16 out
{
    __shared__ char sm[42688];
    float*     Kloc = (float*)(sm);                // [90][36] fp32      12960B
    _Float16*  Vloc = (_Float16*)(sm + 12960);     // [90][40] fp16       7200B
    _Float16*  Khi  = (_Float16*)(sm + 20160);     // [64][40] fp16       5120B
    float*     Xp   = (float*)(sm + 20160);        // [28][36] fp32 (alias Khi)
    _Float16*  Qhi  = (_Float16*)(sm + 25280);     // [32][40] fp16       2560B
    _Float16*  Qlo  = (_Float16*)(sm + 27840);     // [32][40] fp16       2560B
    _Float16*  Aw   = (_Float16*)(sm + 25280);     // [32][72] fp16 (alias Q)
    _Float16*  VpT  = (_Float16*)(sm + 30400);     // [32][72] fp16       4608B
    float*     Ss   = (float*)(sm + 35008);        // [28][68] fp32       7616B
    float*     corr = (float*)(sm + 42624);        // [9]

    const int tid  = threadIdx.x;
    const int w    = tid >> 6, lane = tid & 63;
    const int lr   = lane & 15, quad = lane >> 4;
    const int q8   = quad * 8;
    const int bid  = blockIdx.x;
    const int half = bid & 1;
    const int rest = bid >> 1;
    const int i    = rest % WID;
    const int h    = (rest / WID) & 7;
    const int b    = rest / (WID * NHEADS);
    const int j0   = half * TJ;

    const float scale = log1pf(expf(temp[h])) * sls[0];
    const float inv = 1.0f / scale;

    // ---- prefetch pool biases for this wave's two score sites ----
    float sbias[2][4];
    #pragma unroll
    for (int sl = 0; sl < 2; sl++) {
        int s = 2 * w + sl;
        int mt = s >> 2, nt = s & 3;
        int c_ = nt * 16 + lr;
        #pragma unroll
        for (int r = 0; r < 4; r++) {
            int pr = mt * 16 + quad * 4 + r;
            float bv = 0.f;
            if (pr < TJ && c_ < PLEN) {
                int n = i * WID + j0 + pr;
                bv = tab[rpi[(size_t)n * PLEN + c_] * 8 + h];
            }
            sbias[sl][r] = bv;
        }
    }

    // ---- stage scaled q (hi/lo fp16) ----
    if (tid < 224) {
        int jl = tid >> 3, d4 = tid & 7;
        int n  = i * WID + j0 + jl;
        float4 qv = *reinterpret_cast<const float4*>(&qn[((size_t)(b * NSEQ + n)) * CDIM + h * HDIM + d4 * 4]);
        float4 ev = *reinterpret_cast<const float4*>(&qe[h * HDIM + d4 * 4]);
        float sx = (qv.x + ev.x) * scale, sy = (qv.y + ev.y) * scale;
        float sz = (qv.z + ev.z) * scale, sw = (qv.w + ev.w) * scale;
        half4_t hv = { (_Float16)sx, (_Float16)sy, (_Float16)sz, (_Float16)sw };
        half4_t lv = { (_Float16)(sx - (float)hv.x), (_Float16)(sy - (float)hv.y),
                       (_Float16)(sz - (float)hv.z), (_Float16)(sw - (float)hv.w) };
        *reinterpret_cast<half4_t*>(&Qhi[jl * 40 + d4 * 4]) = hv;
        *reinterpret_cast<half4_t*>(&Qlo[jl * 40 + d4 * 4]) = lv;
    } else {
        int t = tid - 224;               // zero pad rows 28..31
        int jl = 28 + (t >> 3), d4 = t & 7;
        half4_t z = {};
        *reinterpret_cast<half4_t*>(&Qhi[jl * 40 + d4 * 4]) = z;
        *reinterpret_cast<half4_t*>(&Qlo[jl * 40 + d4 * 4]) = z;
    }

    // ---- stage Khi: pool k (normalize!) cols 0..48, lt cols 49..57, 0 pad ----
    for (int idx = tid; idx < 512; idx += 256) {
        int c = idx >> 3, d4 = idx & 7;
        float4 k4 = make_float4(0.f, 0.f, 0.f, 0.f);
        if (c < PLEN)
            k4 = *reinterpret_cast<const float4*>(&kvp[((size_t)(b * PLEN + c)) * 512 + h * HDIM + d4 * 4]);
        float ss2 = k4.x * k4.x + k4.y * k4.y + k4.z * k4.z + k4.w * k4.w;
        ss2 += __shfl_xor(ss2, 1); ss2 += __shfl_xor(ss2, 2); ss2 += __shfl_xor(ss2, 4);
        float rn = 1.0f / fmaxf(sqrtf(ss2), 1e-12f);
        half4_t hv;
        if (c < PLEN) {
            hv.x = (_Float16)(k4.x * rn); hv.y = (_Float16)(k4.y * rn);
            hv.z = (_Float16)(k4.z * rn); hv.w = (_Float16)(k4.w * rn);
        } else if (c < PLEN + 9) {
            int t = c - PLEN;
            hv.x = (_Float16)lt[(h * HDIM + d4 * 4 + 0) * 9 + t];
            hv.y = (_Float16)lt[(h * HDIM + d4 * 4 + 1) * 9 + t];
            hv.z = (_Float16)lt[(h * HDIM + d4 * 4 + 2) * 9 + t];
            hv.w = (_Float16)lt[(h * HDIM + d4 * 4 + 3) * 9 + t];
        } else {
            hv.x = hv.y = hv.z = hv.w = (_Float16)0.f;
        }
        *reinterpret_cast<half4_t*>(&Khi[c * 40 + d4 * 4]) = hv;
    }

    // ---- stage VpT[d][m] (transposed v_pool, fp16) ----
    for (int idx = tid; idx < 512; idx += 256) {
        int m = idx >> 3, d4 = idx & 7;
        if (m < PLEN) {
            float4 v4 = *reinterpret_cast<const float4*>(&kvp[((size_t)(b * PLEN + m)) * 512 + 256 + h * HDIM + d4 * 4]);
            VpT[(d4 * 4 + 0) * 72 + m] = (_Float16)v4.x;
            VpT[(d4 * 4 + 1) * 72 + m] = (_Float16)v4.y;
            VpT[(d4 * 4 + 2) * 72 + m] = (_Float16)v4.z;
            VpT[(d4 * 4 + 3) * 72 + m] = (_Float16)v4.w;
        } else {
            VpT[(d4 * 4 + 0) * 72 + m] = (_Float16)0.f;
            VpT[(d4 * 4 + 1) * 72 + m] = (_Float16)0.f;
            VpT[(d4 * 4 + 2) * 72 + m] = (_Float16)0.f;
            VpT[(d4 * 4 + 3) * 72 + m] = (_Float16)0.f;
        }
    }

    // ---- stage local k (fp32) / v (fp16), v zeroed where invalid ----
    for (int idx = tid; idx < NLOC * 8; idx += 256) {
        int kk = idx >> 3, d4 = idx & 7;
        int r = kk / 30, c = kk % 30;
        int gi = i - 1 + r, gj = j0 - 1 + c;
        bool vld = (gi >= 0) & (gi < WID) & (gj >= 0) & (gj < WID);
        int gic = min(max(gi, 0), WID - 1), gjc = min(max(gj, 0), WID - 1);
        const float* base = &kvb[((size_t)(b * NSEQ + gic * WID + gjc)) * 512 + h * HDIM];
        float4 k4 = *reinterpret_cast<const float4*>(base + d4 * 4);
        float4 v4 = *reinterpret_cast<const float4*>(base + 256 + d4 * 4);
        if (!vld) v4 = make_float4(0.f, 0.f, 0.f, 0.f);
        *reinterpret_cast<float4*>(&Kloc[kk * 36 + d4 * 4]) = k4;
        half4_t hv = { (_Float16)v4.x, (_Float16)v4.y, (_Float16)v4.z, (_Float16)v4.w };
        *reinterpret_cast<half4_t*>(&Vloc[kk * 40 + d4 * 4]) = hv;
    }
    if (tid < 9) {
        float s = 0.f;
        for (int d = 0; d < 32; d++) s += qe[h * 32 + d] * lt[(h * 32 + d) * 9 + tid];
        corr[tid] = lb[h * 9 + tid] - s;
    }
    __syncthreads();

    // ================= score phase =================
    // MFMA: 8 sites (2 m-tiles x 4 n-tiles), 2 per wave, 2 mfma each (q split)
    #pragma unroll
    for (int sl = 0; sl < 2; sl++) {
        int s = 2 * w + sl;
        int mt = s >> 2, nt = s & 3;
        half8 ah = *reinterpret_cast<const half8*>(&Qhi[(mt * 16 + lr) * 40 + q8]);
        half8 al = *reinterpret_cast<const half8*>(&Qlo[(mt * 16 + lr) * 40 + q8]);
        half8 bk = *reinterpret_cast<const half8*>(&Khi[(nt * 16 + lr) * 40 + q8]);
        f32x4 c = {};
        c = __builtin_amdgcn_mfma_f32_16x16x32_f16(ah, bk, c, 0, 0, 0);
        c = __builtin_amdgcn_mfma_f32_16x16x32_f16(al, bk, c, 0, 0, 0);
        int c_ = nt * 16 + lr;
        if (c_ < 58) {
            #pragma unroll
            for (int r = 0; r < 4; r++) {
                int pr = mt * 16 + quad * 4 + r;
                if (pr < TJ) Ss[pr * 68 + 9 + c_] = c[r] + sbias[sl][r];
            }
        }
    }
    // scalar local scores (252 threads)
    if (tid < TJ * 9) {
        int jl = tid / 9, e = tid - jl * 9;
        int gi = i - 1 + e / 3, gj = j0 + jl + (e % 3) - 1;
        bool vld = (gi >= 0) & (gi < WID) & (gj >= 0) & (gj < WID);
        float acc = vld ? rpb[h * 9 + e] : NEGC;
        int col = (e / 3) * 30 + jl + (e % 3);
        #pragma unroll
        for (int d4 = 0; d4 < 8; d4++) {
            float4 k4 = *reinterpret_cast<const float4*>(&Kloc[col * 36 + d4 * 4]);
            half4_t qh = *reinterpret_cast<const half4_t*>(&Qhi[jl * 40 + d4 * 4]);
            half4_t ql = *reinterpret_cast<const half4_t*>(&Qlo[jl * 40 + d4 * 4]);
            acc += ((float)qh.x + (float)ql.x) * k4.x + ((float)qh.y + (float)ql.y) * k4.y
                 + ((float)qh.z + (float)ql.z) * k4.z + ((float)qh.w + (float)ql.w) * k4.w;
        }
        Ss[jl * 68 + e] = acc;
    }
    __syncthreads();

    // ================= softmax =================
    {
        for (int p = 0; p < 7; p++) {
            int jl = w * 7 + p;
            float sc = (lane < 58) ? Ss[jl * 68 + lane] : -INFINITY;
            float mx = sc;
            #pragma unroll
            for (int m = 32; m > 0; m >>= 1) mx = fmaxf(mx, __shfl_xor(mx, m));
            float pe = (lane < 58) ? expf(sc - mx) : 0.f;
            float sum = pe;
            #pragma unroll
            for (int m = 32; m > 0; m >>= 1) sum += __shfl_xor(sum, m);
            float a = pe / sum;
            if (lane < 9) a += Ss[jl * 68 + 58 + lane] * inv + corr[lane];
            if (lane < 58) Ss[jl * 68 + lane] = a;
            // Aw: pool weights (cols 0..48), zero cols 49..63
            if (lane >= 9)
                Aw[jl * 72 + (lane - 9)] = (lane < 58) ? (_Float16)a : (_Float16)0.f;
            else
                Aw[jl * 72 + 55 + lane] = (_Float16)0.f;
        }
        // zero pad rows 28..31 of Aw (one row per wave)
        if (lane < 36) ((int*)Aw)[(28 + w) * 36 + lane] = 0;
    }
    __syncthreads();

    // ================= pool AV via MFMA =================
    {
        int mt = w >> 1, nt = w & 1;     // 4 sites, 1 per wave
        f32x4 c = {};
        #pragma unroll
        for (int kk = 0; kk < 2; kk++) {
            half8 af = *reinterpret_cast<const half8*>(&Aw[(mt * 16 + lr) * 72 + kk * 32 + q8]);
            half8 bv = *reinterpret_cast<const half8*>(&VpT[(nt * 16 + lr) * 72 + kk * 32 + q8]);
            c = __builtin_amdgcn_mfma_f32_16x16x32_f16(af, bv, c, 0, 0, 0);
        }
        int dim = nt * 16 + lr;
        #pragma unroll
        for (int r = 0; r < 4; r++) {
            int pr = mt * 16 + quad * 4 + r;
            if (pr < TJ) Xp[pr * 36 + dim] = c[r];
        }
    }
    __syncthreads();

    // ================= combine: pool (Xp) + local scalar AV =================
    if (tid < 224) {
        int jl = tid >> 3, d4 = tid & 7;
        float4 o = *reinterpret_cast<const float4*>(&Xp[jl * 36 + d4 * 4]);
        #pragma unroll
        for (int e = 0; e < 9; e++) {
            float a = Ss[jl * 68 + e];
            int col = (e / 3) * 30 + jl + (e % 3);
            half4_t vv = *reinterpret_cast<const half4_t*>(&Vloc[col * 40 + d4 * 4]);
            o.x += a * (float)vv.x; o.y += a * (float)vv.y;
            o.z += a * (float)vv.z; o.w += a * (float)vv.w;
        }
        int n = i * WID + j0 + jl;
        ushort4 u;
        u.x = f2bf(o.x); u.y = f2bf(o.y); u.z = f2bf(o.z); u.w = f2bf(o.w);
        *reinterpret_cast<ushort4*>(&ab[((size_t)(b * NSEQ + n)) * CDIM + h * HDIM + d4 * 4]) = u;
    }
}

// ---------------------------------------------------------------------------
// Workspace (floats), total 26,023,936 = 104.1 MB (same bound as prior rounds)
// ---------------------------------------------------------------------------
extern "C" void kernel_launch(void* const* d_in, const int* in_sizes, int n_in,
                              void* d_out, int out_size, void* d_ws, size_t ws_size,
                              hipStream_t stream)
{
    const float* x    = (const float*)d_in[0];
    const float* sls  = (const float*)d_in[1];
    const float* rct  = (const float*)d_in[2];
    const float* q_w  = (const float*)d_in[3];
    const float* q_b  = (const float*)d_in[4];
    const float* qe   = (const float*)d_in[5];
    const float* temp = (const float*)d_in[6];
    const float* kv_w = (const float*)d_in[7];
    const float* kv_b = (const float*)d_in[8];
    const float* sr_w = (const float*)d_in[9];
    const float* sr_b = (const float*)d_in[10];
    const float* ng   = (const float*)d_in[11];
    const float* nb   = (const float*)d_in[12];
    const float* f1w  = (const float*)d_in[13];
    const float* f1b  = (const float*)d_in[14];
    const float* f2w  = (const float*)d_in[15];
    const float* f2b  = (const float*)d_in[16];
    const float* rpb  = (const float*)d_in[17];
    const float* lt   = (const float*)d_in[18];
    const float* lb   = (const float*)d_in[19];
    const float* pw   = (const float*)d_in[20];
    const float* pbi  = (const float*)d_in[21];
    const int*   rpi  = (const int*)d_in[22];

    if (ws_size < (size_t)26023936 * sizeof(float)) return;

    float* ws  = (float*)d_ws;
    float* qn  = ws;
    float* kvbuf = ws + 6422528;
    float* xs  = ws + 19267584;
    float* xp  = ws + 25690112;
    float* kvp = ws + 25790464;
    float* tab = ws + 25991168;
    float* out = (float*)d_out;

    unsigned short* ab   = (unsigned short*)xs;                  // bf16 attn out
    unsigned short* pwt  = (unsigned short*)(xs + 3211264);      // bf16 proj w^T
    unsigned short* xbf  = (unsigned short*)out;                 // bf16 x
    unsigned short* wcat = (unsigned short*)(out + 3211264);     // bf16 [q|kv|sr]^T

    dim3 blk(256);

    // prep: x->bf16, wcat, cpb table (one launch)
    prep_misc<<<7424, blk, 0, stream>>>(x, xbf, q_w, kv_w, sr_w, wcat,
                                        rct, f1w, f1b, f2w, f2b, tab);

    // fused q|kv|sr MFMA GEMM: outputs qn, kvbuf, xs(gelu)
    gemm_bt<<<dim3(8, 196), blk, 0, stream>>>(xbf, wcat, q_b, kv_b, sr_b,
                                              qn, kvbuf, xs);

    // normalize q + k halves (one launch)
    l2norm_both<<<2 * NTOK, blk, 0, stream>>>(qn, kvbuf);

    // 8x8 pool + LayerNorm, fused with proj-weight transpose
    pool_ln_pwt<<<BATCH * PLEN + 256, blk, 0, stream>>>(xs, ng, nb, xp, pw, pwt);

    // pooled kv projection (k left unnormalized; attn normalizes in staging)
    gemm_bias<0><<<dim3(8, 7), blk, 0, stream>>>(xp, kv_w, kv_b, kvp, BATCH * PLEN, 512, 256);

    // fused attention -> bf16 ab
    attn_tile<<<BATCH * NHEADS * WID * 2, blk, 0, stream>>>(
        qn, kvbuf, kvp, tab, rpi, qe, temp, sls, rpb, lt, lb, ab);

    // output projection (MFMA)
    gemm_bt<<<dim3(2, 196), blk, 0, stream>>>(ab, pwt, pbi, pbi, pbi,
                                              out, out, out);
}

// Round 6
// 337.555 us; speedup vs baseline: 3.3695x; 1.1219x over previous
//
#include <hip/hip_runtime.h>
#include <math.h>

#define NSEQ   3136      // N0 = 56*56
#define NTOK   25088     // B * NSEQ
#define BATCH  8
#define WID    56
#define NHEADS 8
#define HDIM   32
#define CDIM   256
#define PLEN   49
#define NEGC  -1000000000.0f

#define TJ     28        // pixels per block (half an image row)
#define NLOC   90        // 3 rows x 30 cols of local keys

typedef __attribute__((ext_vector_type(8))) short short8;
typedef __attribute__((ext_vector_type(4))) float f32x4;
typedef __attribute__((ext_vector_type(8))) _Float16 half8;
typedef __attribute__((ext_vector_type(4))) _Float16 half4_t;

__device__ __forceinline__ float gelu_exact(float x) {
    return 0.5f * x * (1.0f + erff(x * 0.70710678118654752440f));
}

__device__ __forceinline__ unsigned short f2bf(float f) {
    unsigned int u = __float_as_uint(f);
    u += 0x7fffu + ((u >> 16) & 1u);
    return (unsigned short)(u >> 16);
}

__device__ __forceinline__ void gl_lds16(const void* g, void* l) {
    __builtin_amdgcn_global_load_lds(
        (const __attribute__((address_space(1))) void*)g,
        (__attribute__((address_space(3))) void*)l, 16, 0, 0);
}

// ---------------------------------------------------------------------------
// bf16 MFMA GEMM (m97 structure), segmented epilogue with fused per-head
// L2-norm. Head group (32 cols) = two nt-tiles within one wave's 64-col span;
// sum of squares via 4 xor-shuffles (masks 1,2,4,8 stay in the 16-lane group).
// Norm applies exactly when bn < 512 (q segment + kv k-half). NORM=0 for proj.
// ---------------------------------------------------------------------------
template<int NORM>
__global__ __launch_bounds__(256) void gemm_bt(
    const unsigned short* __restrict__ A,
    const unsigned short* __restrict__ Bt,
    const float* __restrict__ b0, const float* __restrict__ b1,
    const float* __restrict__ b2,
    float* __restrict__ o0, float* __restrict__ o1, float* __restrict__ o2)
{
    __shared__ short As[4096];
    __shared__ short Bs[4096];
    const int tid = threadIdx.x;
    const int w = tid >> 6, lane = tid & 63;
    const int bm = blockIdx.y * 128;
    const int bn = blockIdx.x * 128;
    const int m0 = (w >> 1) * 64, n0 = (w & 1) * 64;
    const int lr = lane & 15, q8 = (lane >> 4) * 8, quad = lane >> 4;

    f32x4 acc[4][4] = {};

    const int srow = tid >> 2;
    const int scol = (tid & 3) * 8;
    char* aB = (char*)As + w * 1024;
    char* bB = (char*)Bs + w * 1024;
    const unsigned short* Ap0 = A + (size_t)(bm + srow) * 256 + scol;
    const unsigned short* Ap1 = A + (size_t)(bm + srow + 64) * 256 + scol;
    const unsigned short* Bp0 = Bt + (size_t)(bn + srow) * 256 + scol;
    const unsigned short* Bp1 = Bt + (size_t)(bn + srow + 64) * 256 + scol;

    for (int k0 = 0; k0 < 256; k0 += 32) {
        if (k0) __syncthreads();
        gl_lds16(Ap0 + k0, aB);
        gl_lds16(Ap1 + k0, aB + 4096);
        gl_lds16(Bp0 + k0, bB);
        gl_lds16(Bp1 + k0, bB + 4096);
        __syncthreads();
        short8 af[4], bf[4];
        #pragma unroll
        for (int t = 0; t < 4; t++) {
            af[t] = *reinterpret_cast<const short8*>(&As[(m0 + t * 16 + lr) * 32 + q8]);
            bf[t] = *reinterpret_cast<const short8*>(&Bs[(n0 + t * 16 + lr) * 32 + q8]);
        }
        #pragma unroll
        for (int mt = 0; mt < 4; mt++)
            #pragma unroll
            for (int nt = 0; nt < 4; nt++)
                acc[mt][nt] = __builtin_amdgcn_mfma_f32_16x16x32_bf16(
                    af[mt], bf[nt], acc[mt][nt], 0, 0, 0);
    }

    const float* bp; float* op; int ostr; int c0; bool act = false;
    if (bn < 256)      { bp = b0; op = o0; ostr = 256; c0 = bn; }
    else if (bn < 768) { bp = b1; op = o1; ostr = 512; c0 = bn - 256; }
    else               { bp = b2; op = o2; ostr = 256; c0 = bn - 768; act = true; }
    const bool donorm = NORM && (bn < 512);

    float bv[4];
    #pragma unroll
    for (int nt = 0; nt < 4; nt++) bv[nt] = bp[c0 + n0 + nt * 16 + lr];

    #pragma unroll
    for (int mt = 0; mt < 4; mt++) {
        #pragma unroll
        for (int r = 0; r < 4; r++) {
            float ov[4];
            #pragma unroll
            for (int nt = 0; nt < 4; nt++) ov[nt] = acc[mt][nt][r] + bv[nt];
            if (act) {
                #pragma unroll
                for (int nt = 0; nt < 4; nt++) ov[nt] = gelu_exact(ov[nt]);
            }
            if (donorm) {
                float s01 = ov[0] * ov[0] + ov[1] * ov[1];
                float s23 = ov[2] * ov[2] + ov[3] * ov[3];
                #pragma unroll
                for (int mm = 1; mm < 16; mm <<= 1) {
                    s01 += __shfl_xor(s01, mm);
                    s23 += __shfl_xor(s23, mm);
                }
                float r01 = 1.0f / fmaxf(sqrtf(s01), 1e-12f);
                float r23 = 1.0f / fmaxf(sqrtf(s23), 1e-12f);
                ov[0] *= r01; ov[1] *= r01; ov[2] *= r23; ov[3] *= r23;
            }
            int m = bm + m0 + mt * 16 + quad * 4 + r;
            #pragma unroll
            for (int nt = 0; nt < 4; nt++)
                op[(size_t)m * ostr + c0 + n0 + nt * 16 + lr] = ov[nt];
        }
    }
}

// ---------------------------------------------------------------------------
// Merged prep: [0,6272) x->bf16 | [6272,7296) wcat | [7296,7424) cpb table
// ---------------------------------------------------------------------------
__global__ __launch_bounds__(256) void prep_misc(
    const float* __restrict__ x, unsigned short* __restrict__ xbf,
    const float* __restrict__ qw, const float* __restrict__ kvw,
    const float* __restrict__ srw, unsigned short* __restrict__ wcat,
    const float* __restrict__ rct, const float* __restrict__ fc1w,
    const float* __restrict__ fc1b, const float* __restrict__ fc2w,
    const float* __restrict__ fc2b, float* __restrict__ tab)
{
    int bid = blockIdx.x, tid = threadIdx.x;
    if (bid < 6272) {
        int i = bid * 256 + tid;
        float4 v = reinterpret_cast<const float4*>(x)[i];
        ushort4 u;
        u.x = f2bf(v.x); u.y = f2bf(v.y); u.z = f2bf(v.z); u.w = f2bf(v.w);
        reinterpret_cast<ushort4*>(xbf)[i] = u;
    } else if (bid < 7296) {
        int gid = (bid - 6272) * 256 + tid;
        int n = gid >> 8, k = gid & 255;
        float v;
        if (n < 256)      v = qw[k * 256 + n];
        else if (n < 768) v = kvw[k * 512 + (n - 256)];
        else              v = srw[k * 256 + (n - 768)];
        wcat[gid] = f2bf(v);
    } else {
        int gid = (bid - 7296) * 256 + tid;
        if (gid >= 4096 * 8) return;
        int t = gid >> 3, h = gid & 7;
        float c0 = rct[t * 2 + 0], c1 = rct[t * 2 + 1];
        float acc = 0.f;
        for (int i = 0; i < 512; i++) {
            float hid = fmaxf(c0 * fc1w[i] + c1 * fc1w[512 + i] + fc1b[i], 0.f);
            acc += hid * fc2w[i * 8 + h];
        }
        tab[t * 8 + h] = acc + fc2b[h];
    }
}

// ---------------------------------------------------------------------------
// pool+LN (blocks 0..391) fused with proj-weight transpose (blocks 392..647)
// ---------------------------------------------------------------------------
__global__ __launch_bounds__(256) void pool_ln_pwt(
    const float* __restrict__ xs, const float* __restrict__ g,
    const float* __restrict__ bb, float* __restrict__ xp,
    const float* __restrict__ pw, unsigned short* __restrict__ pwt)
{
    if (blockIdx.x >= BATCH * PLEN) {
        int gid = (blockIdx.x - BATCH * PLEN) * 256 + threadIdx.x;
        int n = gid >> 8, k = gid & 255;
        pwt[gid] = f2bf(pw[k * 256 + n]);
        return;
    }
    int b = blockIdx.x / PLEN, p = blockIdx.x % PLEN;
    int ph = p / 7, pw_ = p % 7;
    int c = threadIdx.x;
    float s = 0.f;
    #pragma unroll
    for (int i = 0; i < 8; i++) {
        int rowpix = (ph * 8 + i) * WID + pw_ * 8;
        const float* base = &xs[((size_t)b * NSEQ + rowpix) * CDIM + c];
        #pragma unroll
        for (int jj = 0; jj < 8; jj++) s += base[(size_t)jj * CDIM];
    }
    s *= (1.f / 64.f);

    float ssum = s, ssq = s * s;
    #pragma unroll
    for (int m = 32; m > 0; m >>= 1) {
        ssum += __shfl_xor(ssum, m);
        ssq  += __shfl_xor(ssq, m);
    }
    __shared__ float r1[4], r2[4];
    int wv = threadIdx.x >> 6;
    if ((threadIdx.x & 63) == 0) { r1[wv] = ssum; r2[wv] = ssq; }
    __syncthreads();
    float tsum = r1[0] + r1[1] + r1[2] + r1[3];
    float tsq  = r2[0] + r2[1] + r2[2] + r2[3];
    float mu  = tsum * (1.f / 256.f);
    float var = tsq * (1.f / 256.f) - mu * mu;
    float o = (s - mu) * rsqrtf(var + 1e-5f) * g[c] + bb[c];
    xp[(size_t)blockIdx.x * CDIM + c] = o;
}

// ---------------------------------------------------------------------------
// fp32 tiled GEMM (tiny pooled-kv projection, M=392).
// ---------------------------------------------------------------------------
template<int ACT>
__global__ __launch_bounds__(256) void gemm_bias(
    const float* __restrict__ A, const float* __restrict__ Bw,
    const float* __restrict__ bias, float* __restrict__ C,
    int M, int N, int K)
{
    __shared__ float Asm[16][68];
    __shared__ float Bsm[16][68];
    const int tid = threadIdx.x;
    const int tx  = tid & 15, ty = tid >> 4;
    const int bm  = blockIdx.y * 64, bn = blockIdx.x * 64;
    float acc[4][4] = {};

    const int am  = tid >> 2;
    const int ak  = (tid & 3) * 4;
    const int bk  = tid >> 4;
    const int bn4 = (tid & 15) * 4;

    for (int k0 = 0; k0 < K; k0 += 16) {
        float4 av = make_float4(0.f, 0.f, 0.f, 0.f);
        if (bm + am < M)
            av = *reinterpret_cast<const float4*>(&A[(size_t)(bm + am) * K + k0 + ak]);
        Asm[ak+0][am] = av.x; Asm[ak+1][am] = av.y; Asm[ak+2][am] = av.z; Asm[ak+3][am] = av.w;

        float4 bv = *reinterpret_cast<const float4*>(&Bw[(size_t)(k0 + bk) * N + bn + bn4]);
        Bsm[bk][bn4+0] = bv.x; Bsm[bk][bn4+1] = bv.y; Bsm[bk][bn4+2] = bv.z; Bsm[bk][bn4+3] = bv.w;
        __syncthreads();

        #pragma unroll
        for (int kk = 0; kk < 16; kk++) {
            float a0 = Asm[kk][ty*4+0], a1 = Asm[kk][ty*4+1], a2 = Asm[kk][ty*4+2], a3 = Asm[kk][ty*4+3];
            float b0 = Bsm[kk][tx*4+0], b1 = Bsm[kk][tx*4+1], b2 = Bsm[kk][tx*4+2], b3 = Bsm[kk][tx*4+3];
            acc[0][0] += a0*b0; acc[0][1] += a0*b1; acc[0][2] += a0*b2; acc[0][3] += a0*b3;
            acc[1][0] += a1*b0; acc[1][1] += a1*b1; acc[1][2] += a1*b2; acc[1][3] += a1*b3;
            acc[2][0] += a2*b0; acc[2][1] += a2*b1; acc[2][2] += a2*b2; acc[2][3] += a2*b3;
            acc[3][0] += a3*b0; acc[3][1] += a3*b1; acc[3][2] += a3*b2; acc[3][3] += a3*b3;
        }
        __syncthreads();
    }

    const int n0 = bn + tx * 4;
    float4 bsv = *reinterpret_cast<const float4*>(&bias[n0]);
    #pragma unroll
    for (int r = 0; r < 4; r++) {
        int m = bm + ty * 4 + r;
        if (m < M) {
            float4 o;
            o.x = acc[r][0] + bsv.x;
            o.y = acc[r][1] + bsv.y;
            o.z = acc[r][2] + bsv.z;
            o.w = acc[r][3] + bsv.w;
            if (ACT == 1) {
                o.x = gelu_exact(o.x); o.y = gelu_exact(o.y);
                o.z = gelu_exact(o.z); o.w = gelu_exact(o.w);
            }
            *reinterpret_cast<float4*>(&C[(size_t)m * N + n0]) = o;
        }
    }
}

// ---------------------------------------------------------------------------
// MFMA fused attention. Block = (b, h, row, half): 28 pixels.
// Local keys fp32 (the softmax top entry is almost always local — fp16 there
// moves the whole distribution; R5 failure). Pool keys fp16 via MFMA.
// LDS liveness-packed to 37.9 KB -> 4 blocks/CU:
//   Kloc region reused for Xp after the score phase;
//   Khi region reused for VpT (staged during the softmax phase).
// ---------------------------------------------------------------------------
__global__ __launch_bounds__(256) void attn_tile(
    const float* __restrict__ qn,   // (B,N,256)  L2-normalized q
    const float* __restrict__ kvb,  // (B,N,512)  [k normalized | v]
    const float* __restrict__ kvp,  // (B,49,512) [k_pool UNnormalized | v_pool]
    const float* __restrict__ tab,  // (4096,8)
    const int*   __restrict__ rpi,  // (N*49)
    const float* __restrict__ qe,   // (8,32)
    const float* __restrict__ temp, // (8)
    const float* __restrict__ sls,  // (1)
    const float* __restrict__ rpb,  // (8,9)
    const float* __restrict__ lt,   // (8,32,9)
    const float* __restrict__ lb,   // (8,9)
    unsigned short* __restrict__ ab)// (B,N,256) bf16 out
{
    __shared__ char sm[37952];
    float*     Kloc = (float*)(sm);                // [90][36] fp32     12960B (score phase)
    float*     Xp   = (float*)(sm);                // [28][36] fp32     (alias, AV phase)
    _Float16*  Vloc = (_Float16*)(sm + 12960);     // [90][40] fp16      7200B
    _Float16*  Khi  = (_Float16*)(sm + 20160);     // [64][40] fp16      5120B (score phase)
    _Float16*  VpT  = (_Float16*)(sm + 20160);     // [32][72] fp16     (alias, AV phase)
    _Float16*  Qhi  = (_Float16*)(sm + 25280);     // [32][40] fp16      2560B (score phase)
    _Float16*  Qlo  = (_Float16*)(sm + 27840);     // [32][40] fp16      2560B (score phase)
    _Float16*  Aw   = (_Float16*)(sm + 25280);     // [32][72] fp16     (alias, AV phase)
    float*     Ss   = (float*)(sm + 30400);        // [28][67] fp32      7504B
    float*     corr = (float*)(sm + 37904);        // [9]

    const int tid  = threadIdx.x;
    const int w    = tid >> 6, lane = tid & 63;
    const int lr   = lane & 15, quad = lane >> 4;
    const int q8   = quad * 8;
    const int bid  = blockIdx.x;
    const int half = bid & 1;
    const int rest = bid >> 1;
    const int i    = rest % WID;
    const int h    = (rest / WID) & 7;
    const int b    = rest / (WID * NHEADS);
    const int j0   = half * TJ;

    const float scale = log1pf(expf(temp[h])) * sls[0];
    const float inv = 1.0f / scale;

    // ---- prefetch pool biases for this wave's two score sites ----
    float sbias[2][4];
    #pragma unroll
    for (int sl = 0; sl < 2; sl++) {
        int s = 2 * w + sl;
        int mt = s >> 2, nt = s & 3;
        int c_ = nt * 16 + lr;
        #pragma unroll
        for (int r = 0; r < 4; r++) {
            int pr = mt * 16 + quad * 4 + r;
            float bv = 0.f;
            if (pr < TJ && c_ < PLEN) {
                int n = i * WID + j0 + pr;
                bv = tab[rpi[(size_t)n * PLEN + c_] * 8 + h];
            }
            sbias[sl][r] = bv;
        }
    }

    // ---- stage scaled q (hi/lo fp16) ----
    if (tid < 224) {
        int jl = tid >> 3, d4 = tid & 7;
        int n  = i * WID + j0 + jl;
        float4 qv = *reinterpret_cast<const float4*>(&qn[((size_t)(b * NSEQ + n)) * CDIM + h * HDIM + d4 * 4]);
        float4 ev = *reinterpret_cast<const float4*>(&qe[h * HDIM + d4 * 4]);
        float sx = (qv.x + ev.x) * scale, sy = (qv.y + ev.y) * scale;
        float sz = (qv.z + ev.z) * scale, sw = (qv.w + ev.w) * scale;
        half4_t hv = { (_Float16)sx, (_Float16)sy, (_Float16)sz, (_Float16)sw };
        half4_t lv = { (_Float16)(sx - (float)hv.x), (_Float16)(sy - (float)hv.y),
                       (_Float16)(sz - (float)hv.z), (_Float16)(sw - (float)hv.w) };
        *reinterpret_cast<half4_t*>(&Qhi[jl * 40 + d4 * 4]) = hv;
        *reinterpret_cast<half4_t*>(&Qlo[jl * 40 + d4 * 4]) = lv;
    } else {
        int t = tid - 224;               // zero pad rows 28..31
        int jl = 28 + (t >> 3), d4 = t & 7;
        half4_t z = {};
        *reinterpret_cast<half4_t*>(&Qhi[jl * 40 + d4 * 4]) = z;
        *reinterpret_cast<half4_t*>(&Qlo[jl * 40 + d4 * 4]) = z;
    }

    // ---- stage Khi: pool k (normalize!) cols 0..48, lt cols 49..57, 0 pad ----
    for (int idx = tid; idx < 512; idx += 256) {
        int c = idx >> 3, d4 = idx & 7;
        float4 k4 = make_float4(0.f, 0.f, 0.f, 0.f);
        if (c < PLEN)
            k4 = *reinterpret_cast<const float4*>(&kvp[((size_t)(b * PLEN + c)) * 512 + h * HDIM + d4 * 4]);
        float ss2 = k4.x * k4.x + k4.y * k4.y + k4.z * k4.z + k4.w * k4.w;
        ss2 += __shfl_xor(ss2, 1); ss2 += __shfl_xor(ss2, 2); ss2 += __shfl_xor(ss2, 4);
        float rn = 1.0f / fmaxf(sqrtf(ss2), 1e-12f);
        half4_t hv;
        if (c < PLEN) {
            hv.x = (_Float16)(k4.x * rn); hv.y = (_Float16)(k4.y * rn);
            hv.z = (_Float16)(k4.z * rn); hv.w = (_Float16)(k4.w * rn);
        } else if (c < PLEN + 9) {
            int t = c - PLEN;
            hv.x = (_Float16)lt[(h * HDIM + d4 * 4 + 0) * 9 + t];
            hv.y = (_Float16)lt[(h * HDIM + d4 * 4 + 1) * 9 + t];
            hv.z = (_Float16)lt[(h * HDIM + d4 * 4 + 2) * 9 + t];
            hv.w = (_Float16)lt[(h * HDIM + d4 * 4 + 3) * 9 + t];
        } else {
            hv.x = hv.y = hv.z = hv.w = (_Float16)0.f;
        }
        *reinterpret_cast<half4_t*>(&Khi[c * 40 + d4 * 4]) = hv;
    }

    // ---- stage local k (fp32) / v (fp16), v zeroed where invalid ----
    for (int idx = tid; idx < NLOC * 8; idx += 256) {
        int kk = idx >> 3, d4 = idx & 7;
        int r = kk / 30, c = kk % 30;
        int gi = i - 1 + r, gj = j0 - 1 + c;
        bool vld = (gi >= 0) & (gi < WID) & (gj >= 0) & (gj < WID);
        int gic = min(max(gi, 0), WID - 1), gjc = min(max(gj, 0), WID - 1);
        const float* base = &kvb[((size_t)(b * NSEQ + gic * WID + gjc)) * 512 + h * HDIM];
        float4 k4 = *reinterpret_cast<const float4*>(base + d4 * 4);
        float4 v4 = *reinterpret_cast<const float4*>(base + 256 + d4 * 4);
        if (!vld) v4 = make_float4(0.f, 0.f, 0.f, 0.f);
        *reinterpret_cast<float4*>(&Kloc[kk * 36 + d4 * 4]) = k4;
        half4_t hv = { (_Float16)v4.x, (_Float16)v4.y, (_Float16)v4.z, (_Float16)v4.w };
        *reinterpret_cast<half4_t*>(&Vloc[kk * 40 + d4 * 4]) = hv;
    }
    if (tid < 9) {
        float s = 0.f;
        for (int d = 0; d < 32; d++) s += qe[h * 32 + d] * lt[(h * 32 + d) * 9 + tid];
        corr[tid] = lb[h * 9 + tid] - s;
    }
    __syncthreads();

    // ================= score phase =================
    #pragma unroll
    for (int sl = 0; sl < 2; sl++) {
        int s = 2 * w + sl;
        int mt = s >> 2, nt = s & 3;
        half8 ah = *reinterpret_cast<const half8*>(&Qhi[(mt * 16 + lr) * 40 + q8]);
        half8 al = *reinterpret_cast<const half8*>(&Qlo[(mt * 16 + lr) * 40 + q8]);
        half8 bk = *reinterpret_cast<const half8*>(&Khi[(nt * 16 + lr) * 40 + q8]);
        f32x4 c = {};
        c = __builtin_amdgcn_mfma_f32_16x16x32_f16(ah, bk, c, 0, 0, 0);
        c = __builtin_amdgcn_mfma_f32_16x16x32_f16(al, bk, c, 0, 0, 0);
        int c_ = nt * 16 + lr;
        if (c_ < 58) {
            #pragma unroll
            for (int r = 0; r < 4; r++) {
                int pr = mt * 16 + quad * 4 + r;
                if (pr < TJ) Ss[pr * 67 + 9 + c_] = c[r] + sbias[sl][r];
            }
        }
    }
    // scalar local scores (252 threads), fp32 k
    if (tid < TJ * 9) {
        int jl = tid / 9, e = tid - jl * 9;
        int gi = i - 1 + e / 3, gj = j0 + jl + (e % 3) - 1;
        bool vld = (gi >= 0) & (gi < WID) & (gj >= 0) & (gj < WID);
        float acc = vld ? rpb[h * 9 + e] : NEGC;
        int col = (e / 3) * 30 + jl + (e % 3);
        #pragma unroll
        for (int d4 = 0; d4 < 8; d4++) {
            float4 k4 = *reinterpret_cast<const float4*>(&Kloc[col * 36 + d4 * 4]);
            half4_t qh = *reinterpret_cast<const half4_t*>(&Qhi[jl * 40 + d4 * 4]);
            half4_t ql = *reinterpret_cast<const half4_t*>(&Qlo[jl * 40 + d4 * 4]);
            acc += ((float)qh.x + (float)ql.x) * k4.x
                 + ((float)qh.y + (float)ql.y) * k4.y
                 + ((float)qh.z + (float)ql.z) * k4.z
                 + ((float)qh.w + (float)ql.w) * k4.w;
        }
        Ss[jl * 67 + e] = acc;
    }
    __syncthreads();

    // ===== softmax (unrolled) + VpT staging into the dead Khi region =====
    {
        // stage VpT[d][m] (transposed v_pool, fp16) — overlaps softmax compute
        for (int idx = tid; idx < 512; idx += 256) {
            int m = idx >> 3, d4 = idx & 7;
            if (m < PLEN) {
                float4 v4 = *reinterpret_cast<const float4*>(&kvp[((size_t)(b * PLEN + m)) * 512 + 256 + h * HDIM + d4 * 4]);
                VpT[(d4 * 4 + 0) * 72 + m] = (_Float16)v4.x;
                VpT[(d4 * 4 + 1) * 72 + m] = (_Float16)v4.y;
                VpT[(d4 * 4 + 2) * 72 + m] = (_Float16)v4.z;
                VpT[(d4 * 4 + 3) * 72 + m] = (_Float16)v4.w;
            } else {
                VpT[(d4 * 4 + 0) * 72 + m] = (_Float16)0.f;
                VpT[(d4 * 4 + 1) * 72 + m] = (_Float16)0.f;
                VpT[(d4 * 4 + 2) * 72 + m] = (_Float16)0.f;
                VpT[(d4 * 4 + 3) * 72 + m] = (_Float16)0.f;
            }
        }
        #pragma unroll
        for (int p = 0; p < 7; p++) {
            int jl = w * 7 + p;
            float sc = (lane < 58) ? Ss[jl * 67 + lane] : -INFINITY;
            float mx = sc;
            #pragma unroll
            for (int m = 32; m > 0; m >>= 1) mx = fmaxf(mx, __shfl_xor(mx, m));
            float pe = (lane < 58) ? __expf(sc - mx) : 0.f;
            float sum = pe;
            #pragma unroll
            for (int m = 32; m > 0; m >>= 1) sum += __shfl_xor(sum, m);
            float a = pe / sum;
            if (lane < 9) a += Ss[jl * 67 + 58 + lane] * inv + corr[lane];
            if (lane < 58) Ss[jl * 67 + lane] = a;
            // Aw (over dead Q region): pool weights cols 0..48, zero 49..63
            if (lane >= 9)
                Aw[jl * 72 + (lane - 9)] = (lane < 58) ? (_Float16)a : (_Float16)0.f;
            else
                Aw[jl * 72 + 55 + lane] = (_Float16)0.f;
        }
        if (lane < 36) ((int*)Aw)[(28 + w) * 36 + lane] = 0;  // pad rows 28..31
    }
    __syncthreads();

    // ================= pool AV via MFMA (Xp over dead Kloc region) ==========
    {
        int mt = w >> 1, nt = w & 1;
        f32x4 c = {};
        #pragma unroll
        for (int kk = 0; kk < 2; kk++) {
            half8 af = *reinterpret_cast<const half8*>(&Aw[(mt * 16 + lr) * 72 + kk * 32 + q8]);
            half8 bv = *reinterpret_cast<const half8*>(&VpT[(nt * 16 + lr) * 72 + kk * 32 + q8]);
            c = __builtin_amdgcn_mfma_f32_16x16x32_f16(af, bv, c, 0, 0, 0);
        }
        int dim = nt * 16 + lr;
        #pragma unroll
        for (int r = 0; r < 4; r++) {
            int pr = mt * 16 + quad * 4 + r;
            if (pr < TJ) Xp[pr * 36 + dim] = c[r];
        }
    }
    __syncthreads();

    // ================= combine: pool (Xp) + local scalar AV =================
    if (tid < 224) {
        int jl = tid >> 3, d4 = tid & 7;
        float4 o = *reinterpret_cast<const float4*>(&Xp[jl * 36 + d4 * 4]);
        #pragma unroll
        for (int e = 0; e < 9; e++) {
            float a = Ss[jl * 67 + e];
            int col = (e / 3) * 30 + jl + (e % 3);
            half4_t vv = *reinterpret_cast<const half4_t*>(&Vloc[col * 40 + d4 * 4]);
            o.x += a * (float)vv.x; o.y += a * (float)vv.y;
            o.z += a * (float)vv.z; o.w += a * (float)vv.w;
        }
        int n = i * WID + j0 + jl;
        ushort4 u;
        u.x = f2bf(o.x); u.y = f2bf(o.y); u.z = f2bf(o.z); u.w = f2bf(o.w);
        *reinterpret_cast<ushort4*>(&ab[((size_t)(b * NSEQ + n)) * CDIM + h * HDIM + d4 * 4]) = u;
    }
}

// ---------------------------------------------------------------------------
// Workspace (floats), total 26,023,936 = 104.1 MB (same bound as prior rounds)
// ---------------------------------------------------------------------------
extern "C" void kernel_launch(void* const* d_in, const int* in_sizes, int n_in,
                              void* d_out, int out_size, void* d_ws, size_t ws_size,
                              hipStream_t stream)
{
    const float* x    = (const float*)d_in[0];
    const float* sls  = (const float*)d_in[1];
    const float* rct  = (const float*)d_in[2];
    const float* q_w  = (const float*)d_in[3];
    const float* q_b  = (const float*)d_in[4];
    const float* qe   = (const float*)d_in[5];
    const float* temp = (const float*)d_in[6];
    const float* kv_w = (const float*)d_in[7];
    const float* kv_b = (const float*)d_in[8];
    const float* sr_w = (const float*)d_in[9];
    const float* sr_b = (const float*)d_in[10];
    const float* ng   = (const float*)d_in[11];
    const float* nb   = (const float*)d_in[12];
    const float* f1w  = (const float*)d_in[13];
    const float* f1b  = (const float*)d_in[14];
    const float* f2w  = (const float*)d_in[15];
    const float* f2b  = (const float*)d_in[16];
    const float* rpb  = (const float*)d_in[17];
    const float* lt   = (const float*)d_in[18];
    const float* lb   = (const float*)d_in[19];
    const float* pw   = (const float*)d_in[20];
    const float* pbi  = (const float*)d_in[21];
    const int*   rpi  = (const int*)d_in[22];

    if (ws_size < (size_t)26023936 * sizeof(float)) return;

    float* ws  = (float*)d_ws;
    float* qn  = ws;
    float* kvbuf = ws + 6422528;
    float* xs  = ws + 19267584;
    float* xp  = ws + 25690112;
    float* kvp = ws + 25790464;
    float* tab = ws + 25991168;
    float* out = (float*)d_out;

    unsigned short* ab   = (unsigned short*)xs;                  // bf16 attn out
    unsigned short* pwt  = (unsigned short*)(xs + 3211264);      // bf16 proj w^T
    unsigned short* xbf  = (unsigned short*)out;                 // bf16 x
    unsigned short* wcat = (unsigned short*)(out + 3211264);     // bf16 [q|kv|sr]^T

    dim3 blk(256);

    // prep: x->bf16, wcat, cpb table (one launch)
    prep_misc<<<7424, blk, 0, stream>>>(x, xbf, q_w, kv_w, sr_w, wcat,
                                        rct, f1w, f1b, f2w, f2b, tab);

    // fused q|kv|sr MFMA GEMM with fused L2-norm epilogue (norm for bn<512)
    gemm_bt<1><<<dim3(8, 196), blk, 0, stream>>>(xbf, wcat, q_b, kv_b, sr_b,
                                                 qn, kvbuf, xs);

    // 8x8 pool + LayerNorm, fused with proj-weight transpose
    pool_ln_pwt<<<BATCH * PLEN + 256, blk, 0, stream>>>(xs, ng, nb, xp, pw, pwt);

    // pooled kv projection (k left unnormalized; attn normalizes in staging)
    gemm_bias<0><<<dim3(8, 7), blk, 0, stream>>>(xp, kv_w, kv_b, kvp, BATCH * PLEN, 512, 256);

    // fused attention -> bf16 ab
    attn_tile<<<BATCH * NHEADS * WID * 2, blk, 0, stream>>>(
        qn, kvbuf, kvp, tab, rpi, qe, temp, sls, rpb, lt, lb, ab);

    // output projection (MFMA, no norm)
    gemm_bt<0><<<dim3(2, 196), blk, 0, stream>>>(ab, pwt, pbi, pbi, pbi,
                                                 out, out, out);
}

// Round 8
// 327.880 us; speedup vs baseline: 3.4689x; 1.0295x over previous
//
#include <hip/hip_runtime.h>
#include <math.h>

#define NSEQ   3136      // N0 = 56*56
#define NTOK   25088     // B * NSEQ
#define BATCH  8
#define WID    56
#define NHEADS 8
#define HDIM   32
#define CDIM   256
#define PLEN   49
#define NEGC  -1000000000.0f

#define TJ     28        // pixels per block (half an image row)
#define NLOC   90        // 3 rows x 30 cols of local keys
#define KT     168       // A_all / V_T stride in halfs (160 keys + pad)

typedef __attribute__((ext_vector_type(8))) short short8;
typedef __attribute__((ext_vector_type(4))) float f32x4;
typedef __attribute__((ext_vector_type(8))) _Float16 half8;
typedef __attribute__((ext_vector_type(4))) _Float16 half4_t;

__device__ __forceinline__ float gelu_exact(float x) {
    return 0.5f * x * (1.0f + erff(x * 0.70710678118654752440f));
}

__device__ __forceinline__ unsigned short f2bf(float f) {
    unsigned int u = __float_as_uint(f);
    u += 0x7fffu + ((u >> 16) & 1u);
    return (unsigned short)(u >> 16);
}

__device__ __forceinline__ void gl_lds16(const void* g, void* l) {
    __builtin_amdgcn_global_load_lds(
        (const __attribute__((address_space(1))) void*)g,
        (__attribute__((address_space(3))) void*)l, 16, 0, 0);
}

// ---------------------------------------------------------------------------
// bf16 MFMA GEMM (m97 structure), segmented epilogue with fused per-head
// L2-norm (exact R6 version — proven). Norm when bn < 512 (q + kv k-half).
// ---------------------------------------------------------------------------
template<int NORM>
__global__ __launch_bounds__(256) void gemm_bt(
    const unsigned short* __restrict__ A,
    const unsigned short* __restrict__ Bt,
    const float* __restrict__ b0, const float* __restrict__ b1,
    const float* __restrict__ b2,
    float* __restrict__ o0, float* __restrict__ o1, float* __restrict__ o2)
{
    __shared__ short As[4096];
    __shared__ short Bs[4096];
    const int tid = threadIdx.x;
    const int w = tid >> 6, lane = tid & 63;
    const int bm = blockIdx.y * 128;
    const int bn = blockIdx.x * 128;
    const int m0 = (w >> 1) * 64, n0 = (w & 1) * 64;
    const int lr = lane & 15, q8 = (lane >> 4) * 8, quad = lane >> 4;

    f32x4 acc[4][4] = {};

    const int srow = tid >> 2;
    const int scol = (tid & 3) * 8;
    char* aB = (char*)As + w * 1024;
    char* bB = (char*)Bs + w * 1024;
    const unsigned short* Ap0 = A + (size_t)(bm + srow) * 256 + scol;
    const unsigned short* Ap1 = A + (size_t)(bm + srow + 64) * 256 + scol;
    const unsigned short* Bp0 = Bt + (size_t)(bn + srow) * 256 + scol;
    const unsigned short* Bp1 = Bt + (size_t)(bn + srow + 64) * 256 + scol;

    for (int k0 = 0; k0 < 256; k0 += 32) {
        if (k0) __syncthreads();
        gl_lds16(Ap0 + k0, aB);
        gl_lds16(Ap1 + k0, aB + 4096);
        gl_lds16(Bp0 + k0, bB);
        gl_lds16(Bp1 + k0, bB + 4096);
        __syncthreads();
        short8 af[4], bf[4];
        #pragma unroll
        for (int t = 0; t < 4; t++) {
            af[t] = *reinterpret_cast<const short8*>(&As[(m0 + t * 16 + lr) * 32 + q8]);
            bf[t] = *reinterpret_cast<const short8*>(&Bs[(n0 + t * 16 + lr) * 32 + q8]);
        }
        #pragma unroll
        for (int mt = 0; mt < 4; mt++)
            #pragma unroll
            for (int nt = 0; nt < 4; nt++)
                acc[mt][nt] = __builtin_amdgcn_mfma_f32_16x16x32_bf16(
                    af[mt], bf[nt], acc[mt][nt], 0, 0, 0);
    }

    const float* bp; float* op; int ostr; int c0; bool act = false;
    if (bn < 256)      { bp = b0; op = o0; ostr = 256; c0 = bn; }
    else if (bn < 768) { bp = b1; op = o1; ostr = 512; c0 = bn - 256; }
    else               { bp = b2; op = o2; ostr = 256; c0 = bn - 768; act = true; }
    const bool donorm = NORM && (bn < 512);

    float bv[4];
    #pragma unroll
    for (int nt = 0; nt < 4; nt++) bv[nt] = bp[c0 + n0 + nt * 16 + lr];

    #pragma unroll
    for (int mt = 0; mt < 4; mt++) {
        #pragma unroll
        for (int r = 0; r < 4; r++) {
            float ov[4];
            #pragma unroll
            for (int nt = 0; nt < 4; nt++) ov[nt] = acc[mt][nt][r] + bv[nt];
            if (act) {
                #pragma unroll
                for (int nt = 0; nt < 4; nt++) ov[nt] = gelu_exact(ov[nt]);
            }
            if (donorm) {
                float s01 = ov[0] * ov[0] + ov[1] * ov[1];
                float s23 = ov[2] * ov[2] + ov[3] * ov[3];
                #pragma unroll
                for (int mm = 1; mm < 16; mm <<= 1) {
                    s01 += __shfl_xor(s01, mm);
                    s23 += __shfl_xor(s23, mm);
                }
                float r01 = 1.0f / fmaxf(sqrtf(s01), 1e-12f);
                float r23 = 1.0f / fmaxf(sqrtf(s23), 1e-12f);
                ov[0] *= r01; ov[1] *= r01; ov[2] *= r23; ov[3] *= r23;
            }
            int m = bm + m0 + mt * 16 + quad * 4 + r;
            #pragma unroll
            for (int nt = 0; nt < 4; nt++)
                op[(size_t)m * ostr + c0 + n0 + nt * 16 + lr] = ov[nt];
        }
    }
}

// ---------------------------------------------------------------------------
// Merged prep: [0,6272) x->bf16 | [6272,7296) wcat | [7296,7424) cpb table
// ---------------------------------------------------------------------------
__global__ __launch_bounds__(256) void prep_misc(
    const float* __restrict__ x, unsigned short* __restrict__ xbf,
    const float* __restrict__ qw, const float* __restrict__ kvw,
    const float* __restrict__ srw, unsigned short* __restrict__ wcat,
    const float* __restrict__ rct, const float* __restrict__ fc1w,
    const float* __restrict__ fc1b, const float* __restrict__ fc2w,
    const float* __restrict__ fc2b, float* __restrict__ tab)
{
    int bid = blockIdx.x, tid = threadIdx.x;
    if (bid < 6272) {
        int i = bid * 256 + tid;
        float4 v = reinterpret_cast<const float4*>(x)[i];
        ushort4 u;
        u.x = f2bf(v.x); u.y = f2bf(v.y); u.z = f2bf(v.z); u.w = f2bf(v.w);
        reinterpret_cast<ushort4*>(xbf)[i] = u;
    } else if (bid < 7296) {
        int gid = (bid - 6272) * 256 + tid;
        int n = gid >> 8, k = gid & 255;
        float v;
        if (n < 256)      v = qw[k * 256 + n];
        else if (n < 768) v = kvw[k * 512 + (n - 256)];
        else              v = srw[k * 256 + (n - 768)];
        wcat[gid] = f2bf(v);
    } else {
        int gid = (bid - 7296) * 256 + tid;
        if (gid >= 4096 * 8) return;
        int t = gid >> 3, h = gid & 7;
        float c0 = rct[t * 2 + 0], c1 = rct[t * 2 + 1];
        float acc = 0.f;
        for (int i = 0; i < 512; i++) {
            float hid = fmaxf(c0 * fc1w[i] + c1 * fc1w[512 + i] + fc1b[i], 0.f);
            acc += hid * fc2w[i * 8 + h];
        }
        tab[t * 8 + h] = acc + fc2b[h];
    }
}

// ---------------------------------------------------------------------------
// 8x8 average pool of gelu'd sr output + LayerNorm -> fp32 xp.
// (pwt transpose REMOVED from this kernel: it raced with the xs reads.)
// ---------------------------------------------------------------------------
__global__ __launch_bounds__(256) void pool_ln(
    const float* __restrict__ xs, const float* __restrict__ g,
    const float* __restrict__ bb, float* __restrict__ xp)
{
    int b = blockIdx.x / PLEN, p = blockIdx.x % PLEN;
    int ph = p / 7, pw_ = p % 7;
    int c = threadIdx.x;
    float s = 0.f;
    #pragma unroll
    for (int i = 0; i < 8; i++) {
        int rowpix = (ph * 8 + i) * WID + pw_ * 8;
        const float* base = &xs[((size_t)b * NSEQ + rowpix) * CDIM + c];
        #pragma unroll
        for (int jj = 0; jj < 8; jj++) s += base[(size_t)jj * CDIM];
    }
    s *= (1.f / 64.f);

    float ssum = s, ssq = s * s;
    #pragma unroll
    for (int m = 32; m > 0; m >>= 1) {
        ssum += __shfl_xor(ssum, m);
        ssq  += __shfl_xor(ssq, m);
    }
    __shared__ float r1[4], r2[4];
    int wv = threadIdx.x >> 6;
    if ((threadIdx.x & 63) == 0) { r1[wv] = ssum; r2[wv] = ssq; }
    __syncthreads();
    float tsum = r1[0] + r1[1] + r1[2] + r1[3];
    float tsq  = r2[0] + r2[1] + r2[2] + r2[3];
    float mu  = tsum * (1.f / 256.f);
    float var = tsq * (1.f / 256.f) - mu * mu;
    float o = (s - mu) * rsqrtf(var + 1e-5f) * g[c] + bb[c];
    xp[(size_t)blockIdx.x * CDIM + c] = o;
}

// ---------------------------------------------------------------------------
// fp32 kvp GEMM (M=392, N=512, K=256) + pwt transpose on the extra grid row.
// Runs AFTER pool_ln in stream order, so the pwt write into the (now dead)
// xs region cannot race with pool reads.
// ---------------------------------------------------------------------------
__global__ __launch_bounds__(256) void kvp_pwt(
    const float* __restrict__ A, const float* __restrict__ Bw,
    const float* __restrict__ bias, float* __restrict__ C,
    const float* __restrict__ pw, unsigned short* __restrict__ pwt)
{
    if (blockIdx.y == 7) {
        int base = blockIdx.x * 256 + threadIdx.x;   // 0..2047
        for (int t = base; t < 65536; t += 2048) {
            int n = t >> 8, k = t & 255;
            pwt[t] = f2bf(pw[k * 256 + n]);
        }
        return;
    }
    const int M = BATCH * PLEN, N = 512, K = 256;
    __shared__ float Asm[16][68];
    __shared__ float Bsm[16][68];
    const int tid = threadIdx.x;
    const int tx  = tid & 15, ty = tid >> 4;
    const int bm  = blockIdx.y * 64, bn = blockIdx.x * 64;
    float acc[4][4] = {};

    const int am  = tid >> 2;
    const int ak  = (tid & 3) * 4;
    const int bk  = tid >> 4;
    const int bn4 = (tid & 15) * 4;

    for (int k0 = 0; k0 < K; k0 += 16) {
        float4 av = make_float4(0.f, 0.f, 0.f, 0.f);
        if (bm + am < M)
            av = *reinterpret_cast<const float4*>(&A[(size_t)(bm + am) * K + k0 + ak]);
        Asm[ak+0][am] = av.x; Asm[ak+1][am] = av.y; Asm[ak+2][am] = av.z; Asm[ak+3][am] = av.w;

        float4 bv = *reinterpret_cast<const float4*>(&Bw[(size_t)(k0 + bk) * N + bn + bn4]);
        Bsm[bk][bn4+0] = bv.x; Bsm[bk][bn4+1] = bv.y; Bsm[bk][bn4+2] = bv.z; Bsm[bk][bn4+3] = bv.w;
        __syncthreads();

        #pragma unroll
        for (int kk = 0; kk < 16; kk++) {
            float a0 = Asm[kk][ty*4+0], a1 = Asm[kk][ty*4+1], a2 = Asm[kk][ty*4+2], a3 = Asm[kk][ty*4+3];
            float b0 = Bsm[kk][tx*4+0], b1 = Bsm[kk][tx*4+1], b2 = Bsm[kk][tx*4+2], b3 = Bsm[kk][tx*4+3];
            acc[0][0] += a0*b0; acc[0][1] += a0*b1; acc[0][2] += a0*b2; acc[0][3] += a0*b3;
            acc[1][0] += a1*b0; acc[1][1] += a1*b1; acc[1][2] += a1*b2; acc[1][3] += a1*b3;
            acc[2][0] += a2*b0; acc[2][1] += a2*b1; acc[2][2] += a2*b2; acc[2][3] += a2*b3;
            acc[3][0] += a3*b0; acc[3][1] += a3*b1; acc[3][2] += a3*b2; acc[3][3] += a3*b3;
        }
        __syncthreads();
    }

    const int n0 = bn + tx * 4;
    float4 bsv = *reinterpret_cast<const float4*>(&bias[n0]);
    #pragma unroll
    for (int r = 0; r < 4; r++) {
        int m = bm + ty * 4 + r;
        if (m < M) {
            float4 o;
            o.x = acc[r][0] + bsv.x;
            o.y = acc[r][1] + bsv.y;
            o.z = acc[r][2] + bsv.z;
            o.w = acc[r][3] + bsv.w;
            *reinterpret_cast<float4*>(&C[(size_t)m * N + n0]) = o;
        }
    }
}

// ---------------------------------------------------------------------------
// MFMA fused attention, unified-AV version (R7 structure, R6 numerics).
// Phase A: Kloc fp32 [90][36] | Khi fp16 [58][40] | Qhi/Qlo [32][40]
// Phase B (aliased): A_all [32][KT] | V_T [32][KT]
// Persistent: Ss [28][67] fp32 | corr[9].  Peak 29.6 KB -> 5 blocks/CU.
// k_pool normalized here (fp32 shuffle) from the UNnormalized fp32 kvp.
// ---------------------------------------------------------------------------
__global__ __launch_bounds__(256) void attn_tile(
    const float* __restrict__ qn,   // (B,N,256)  L2-normalized q
    const float* __restrict__ kvb,  // (B,N,512)  [k normalized | v]
    const float* __restrict__ kvp,  // (B,49,512) [k_pool UNnormalized | v_pool]
    const float* __restrict__ tab,  // (4096,8)
    const int*   __restrict__ rpi,  // (N*49)
    const float* __restrict__ qe,   // (8,32)
    const float* __restrict__ temp, // (8)
    const float* __restrict__ sls,  // (1)
    const float* __restrict__ rpb,  // (8,9)
    const float* __restrict__ lt,   // (8,32,9)
    const float* __restrict__ lb,   // (8,9)
    unsigned short* __restrict__ ab)// (B,N,256) bf16 out
{
    __shared__ char sm[30272];
    float*     Kloc = (float*)(sm);                // [90][36] fp32  12960  (A)
    _Float16*  Khi  = (_Float16*)(sm + 12960);     // [58][40] fp16   4640  (A)
    _Float16*  Qhi  = (_Float16*)(sm + 17600);     // [32][40] fp16   2560  (A)
    _Float16*  Qlo  = (_Float16*)(sm + 20160);     // [32][40] fp16   2560  (A)
    _Float16*  Aall = (_Float16*)(sm);             // [32][KT] fp16  10752  (B)
    _Float16*  VT   = (_Float16*)(sm + 10752);     // [32][KT] fp16  10752  (B)
    float*     Ss   = (float*)(sm + 22720);        // [28][67] fp32   7504
    float*     corr = (float*)(sm + 30224);        // [9]

    const int tid  = threadIdx.x;
    const int w    = tid >> 6, lane = tid & 63;
    const int lr   = lane & 15, quad = lane >> 4;
    const int q8   = quad * 8;
    const int bid  = blockIdx.x;
    const int half = bid & 1;
    const int rest = bid >> 1;
    const int i    = rest % WID;
    const int h    = (rest / WID) & 7;
    const int b    = rest / (WID * NHEADS);
    const int j0   = half * TJ;

    const float scale = log1pf(expf(temp[h])) * sls[0];
    const float inv = 1.0f / scale;

    // ---- prefetch pool biases for this wave's two score sites ----
    float sbias[2][4];
    #pragma unroll
    for (int sl = 0; sl < 2; sl++) {
        int s = 2 * w + sl;
        int mt = s >> 2, nt = s & 3;
        int c_ = nt * 16 + lr;
        #pragma unroll
        for (int r = 0; r < 4; r++) {
            int pr = mt * 16 + quad * 4 + r;
            float bv = 0.f;
            if (pr < TJ && c_ < PLEN) {
                int n = i * WID + j0 + pr;
                bv = tab[rpi[(size_t)n * PLEN + c_] * 8 + h];
            }
            sbias[sl][r] = bv;
        }
    }

    // ---- stage scaled q (hi/lo fp16), zero-pad rows 28..31 ----
    if (tid < 224) {
        int jl = tid >> 3, d4 = tid & 7;
        int n  = i * WID + j0 + jl;
        float4 qv = *reinterpret_cast<const float4*>(&qn[((size_t)(b * NSEQ + n)) * CDIM + h * HDIM + d4 * 4]);
        float4 ev = *reinterpret_cast<const float4*>(&qe[h * HDIM + d4 * 4]);
        float sx = (qv.x + ev.x) * scale, sy = (qv.y + ev.y) * scale;
        float sz = (qv.z + ev.z) * scale, sw = (qv.w + ev.w) * scale;
        half4_t hv = { (_Float16)sx, (_Float16)sy, (_Float16)sz, (_Float16)sw };
        half4_t lv = { (_Float16)(sx - (float)hv.x), (_Float16)(sy - (float)hv.y),
                       (_Float16)(sz - (float)hv.z), (_Float16)(sw - (float)hv.w) };
        *reinterpret_cast<half4_t*>(&Qhi[jl * 40 + d4 * 4]) = hv;
        *reinterpret_cast<half4_t*>(&Qlo[jl * 40 + d4 * 4]) = lv;
    } else {
        int t = tid - 224;
        int jl = 28 + (t >> 3), d4 = t & 7;
        half4_t z = {};
        *reinterpret_cast<half4_t*>(&Qhi[jl * 40 + d4 * 4]) = z;
        *reinterpret_cast<half4_t*>(&Qlo[jl * 40 + d4 * 4]) = z;
    }

    // ---- stage Khi: pool k (fp32-normalize here) cols 0..48, lt 49..57 ----
    for (int idx = tid; idx < 58 * 8; idx += 256) {
        int c = idx >> 3, d4 = idx & 7;
        half4_t hv;
        if (c < PLEN) {
            float4 k4 = *reinterpret_cast<const float4*>(&kvp[((size_t)(b * PLEN + c)) * 512 + h * HDIM + d4 * 4]);
            float ss2 = k4.x * k4.x + k4.y * k4.y + k4.z * k4.z + k4.w * k4.w;
            ss2 += __shfl_xor(ss2, 1); ss2 += __shfl_xor(ss2, 2); ss2 += __shfl_xor(ss2, 4);
            float rn = 1.0f / fmaxf(sqrtf(ss2), 1e-12f);
            hv.x = (_Float16)(k4.x * rn); hv.y = (_Float16)(k4.y * rn);
            hv.z = (_Float16)(k4.z * rn); hv.w = (_Float16)(k4.w * rn);
        } else {
            int t = c - PLEN;
            hv.x = (_Float16)lt[(h * HDIM + d4 * 4 + 0) * 9 + t];
            hv.y = (_Float16)lt[(h * HDIM + d4 * 4 + 1) * 9 + t];
            hv.z = (_Float16)lt[(h * HDIM + d4 * 4 + 2) * 9 + t];
            hv.w = (_Float16)lt[(h * HDIM + d4 * 4 + 3) * 9 + t];
        }
        *reinterpret_cast<half4_t*>(&Khi[c * 40 + d4 * 4]) = hv;
    }

    // ---- stage local k (fp32) ----
    for (int idx = tid; idx < NLOC * 8; idx += 256) {
        int kk = idx >> 3, d4 = idx & 7;
        int r = kk / 30, c = kk % 30;
        int gi = i - 1 + r, gj = j0 - 1 + c;
        int gic = min(max(gi, 0), WID - 1), gjc = min(max(gj, 0), WID - 1);
        const float* base = &kvb[((size_t)(b * NSEQ + gic * WID + gjc)) * 512 + h * HDIM];
        *reinterpret_cast<float4*>(&Kloc[kk * 36 + d4 * 4]) =
            *reinterpret_cast<const float4*>(base + d4 * 4);
    }
    if (tid < 9) {
        float s = 0.f;
        for (int d = 0; d < 32; d++) s += qe[h * 32 + d] * lt[(h * 32 + d) * 9 + tid];
        corr[tid] = lb[h * 9 + tid] - s;
    }
    __syncthreads();   // S1

    // ================= score phase =================
    #pragma unroll
    for (int sl = 0; sl < 2; sl++) {
        int s = 2 * w + sl;
        int mt = s >> 2, nt = s & 3;
        half8 ah = *reinterpret_cast<const half8*>(&Qhi[(mt * 16 + lr) * 40 + q8]);
        half8 al = *reinterpret_cast<const half8*>(&Qlo[(mt * 16 + lr) * 40 + q8]);
        half8 bk = *reinterpret_cast<const half8*>(&Khi[(nt * 16 + lr) * 40 + q8]);
        f32x4 c = {};
        c = __builtin_amdgcn_mfma_f32_16x16x32_f16(ah, bk, c, 0, 0, 0);
        c = __builtin_amdgcn_mfma_f32_16x16x32_f16(al, bk, c, 0, 0, 0);
        int c_ = nt * 16 + lr;
        if (c_ < 58) {
            #pragma unroll
            for (int r = 0; r < 4; r++) {
                int pr = mt * 16 + quad * 4 + r;
                if (pr < TJ) Ss[pr * 67 + 9 + c_] = c[r] + sbias[sl][r];
            }
        }
    }
    // scalar local scores (252 threads), fp32 k
    if (tid < TJ * 9) {
        int jl = tid / 9, e = tid - jl * 9;
        int gi = i - 1 + e / 3, gj = j0 + jl + (e % 3) - 1;
        bool vld = (gi >= 0) & (gi < WID) & (gj >= 0) & (gj < WID);
        float acc = vld ? rpb[h * 9 + e] : NEGC;
        int col = (e / 3) * 30 + jl + (e % 3);
        #pragma unroll
        for (int d4 = 0; d4 < 8; d4++) {
            float4 k4 = *reinterpret_cast<const float4*>(&Kloc[col * 36 + d4 * 4]);
            half4_t qh = *reinterpret_cast<const half4_t*>(&Qhi[jl * 40 + d4 * 4]);
            half4_t ql = *reinterpret_cast<const half4_t*>(&Qlo[jl * 40 + d4 * 4]);
            acc += ((float)qh.x + (float)ql.x) * k4.x
                 + ((float)qh.y + (float)ql.y) * k4.y
                 + ((float)qh.z + (float)ql.z) * k4.z
                 + ((float)qh.w + (float)ql.w) * k4.w;
        }
        Ss[jl * 67 + e] = acc;
    }
    __syncthreads();   // S2 — phase-A LDS regions now dead

    // ===== phase B: stage V_T (loads overlap softmax), zero A_all =====
    for (int idx = tid; idx < NLOC * 8; idx += 256) {
        int kk = idx >> 3, d4 = idx & 7;
        int r = kk / 30, c = kk % 30;
        int gi = i - 1 + r, gj = j0 - 1 + c;
        bool vld = (gi >= 0) & (gi < WID) & (gj >= 0) & (gj < WID);
        int gic = min(max(gi, 0), WID - 1), gjc = min(max(gj, 0), WID - 1);
        float4 v4 = *reinterpret_cast<const float4*>(
            &kvb[((size_t)(b * NSEQ + gic * WID + gjc)) * 512 + 256 + h * HDIM + d4 * 4]);
        if (!vld) v4 = make_float4(0.f, 0.f, 0.f, 0.f);
        VT[(d4 * 4 + 0) * KT + kk] = (_Float16)v4.x;
        VT[(d4 * 4 + 1) * KT + kk] = (_Float16)v4.y;
        VT[(d4 * 4 + 2) * KT + kk] = (_Float16)v4.z;
        VT[(d4 * 4 + 3) * KT + kk] = (_Float16)v4.w;
    }
    for (int idx = tid; idx < PLEN * 8; idx += 256) {
        int m = idx >> 3, d4 = idx & 7;
        float4 v4 = *reinterpret_cast<const float4*>(
            &kvp[((size_t)(b * PLEN + m)) * 512 + 256 + h * HDIM + d4 * 4]);
        VT[(d4 * 4 + 0) * KT + 96 + m] = (_Float16)v4.x;
        VT[(d4 * 4 + 1) * KT + 96 + m] = (_Float16)v4.y;
        VT[(d4 * 4 + 2) * KT + 96 + m] = (_Float16)v4.z;
        VT[(d4 * 4 + 3) * KT + 96 + m] = (_Float16)v4.w;
    }
    // zero VT pad cols 90..95 and 145..159
    for (int idx = tid; idx < 32 * 6; idx += 256) {
        int d = idx / 6, c = idx % 6;
        VT[d * KT + 90 + c] = (_Float16)0.f;
    }
    for (int idx = tid; idx < 32 * 15; idx += 256) {
        int d = idx / 15, c = idx % 15;
        VT[d * KT + 145 + c] = (_Float16)0.f;
    }
    // zero this wave's A_all rows (wave-synchronous vs scatter below)
    for (int t = lane; t < 7 * (KT / 2); t += 64) {
        int row = w * 7 + t / (KT / 2);
        ((int*)Aall)[row * (KT / 2) + t % (KT / 2)] = 0;
    }

    // ================= softmax + scatter into A_all =================
    #pragma unroll
    for (int p = 0; p < 7; p++) {
        int jl = w * 7 + p;
        float sc = (lane < 58) ? Ss[jl * 67 + lane] : -INFINITY;
        float mx = sc;
        #pragma unroll
        for (int m = 32; m > 0; m >>= 1) mx = fmaxf(mx, __shfl_xor(mx, m));
        float pe = (lane < 58) ? __expf(sc - mx) : 0.f;
        float sum = pe;
        #pragma unroll
        for (int m = 32; m > 0; m >>= 1) sum += __shfl_xor(sum, m);
        float a = pe / sum;
        if (lane < 9) {
            a += Ss[jl * 67 + 58 + lane] * inv + corr[lane];
            int col = (lane / 3) * 30 + jl + (lane % 3);
            Aall[jl * KT + col] = (_Float16)a;
        } else if (lane < 58) {
            Aall[jl * KT + 96 + (lane - 9)] = (_Float16)a;
        }
    }
    __syncthreads();   // S3

    // ================= unified AV via MFMA, direct bf16 store ===============
    {
        int mt = w >> 1, nt = w & 1;
        f32x4 c = {};
        #pragma unroll
        for (int kk = 0; kk < 5; kk++) {
            half8 af = *reinterpret_cast<const half8*>(&Aall[(mt * 16 + lr) * KT + kk * 32 + q8]);
            half8 bv = *reinterpret_cast<const half8*>(&VT[(nt * 16 + lr) * KT + kk * 32 + q8]);
            c = __builtin_amdgcn_mfma_f32_16x16x32_f16(af, bv, c, 0, 0, 0);
        }
        int dim = nt * 16 + lr;
        #pragma unroll
        for (int r = 0; r < 4; r++) {
            int pr = mt * 16 + quad * 4 + r;
            if (pr < TJ) {
                int n = i * WID + j0 + pr;
                ab[((size_t)(b * NSEQ + n)) * CDIM + h * HDIM + dim] = f2bf(c[r]);
            }
        }
    }
}

// ---------------------------------------------------------------------------
// Workspace (floats), total 26,023,936 = 104.1 MB:
//   qn @0 | kvbuf @6422528 | xs @19267584 | xp @25690112 (fp32)
//   kvp @25790464 | tab @25991168
// xs region: ab bf16 [0:3211264) halfs; pwt bf16 at float offset 3211264 —
//   written by kvp_pwt AFTER pool_ln completed (stream order; no race).
// d_out scratch until proj: xbf [0:3211264) halfs, wcat [3211264:3342336).
// ---------------------------------------------------------------------------
extern "C" void kernel_launch(void* const* d_in, const int* in_sizes, int n_in,
                              void* d_out, int out_size, void* d_ws, size_t ws_size,
                              hipStream_t stream)
{
    const float* x    = (const float*)d_in[0];
    const float* sls  = (const float*)d_in[1];
    const float* rct  = (const float*)d_in[2];
    const float* q_w  = (const float*)d_in[3];
    const float* q_b  = (const float*)d_in[4];
    const float* qe   = (const float*)d_in[5];
    const float* temp = (const float*)d_in[6];
    const float* kv_w = (const float*)d_in[7];
    const float* kv_b = (const float*)d_in[8];
    const float* sr_w = (const float*)d_in[9];
    const float* sr_b = (const float*)d_in[10];
    const float* ng   = (const float*)d_in[11];
    const float* nb   = (const float*)d_in[12];
    const float* f1w  = (const float*)d_in[13];
    const float* f1b  = (const float*)d_in[14];
    const float* f2w  = (const float*)d_in[15];
    const float* f2b  = (const float*)d_in[16];
    const float* rpb  = (const float*)d_in[17];
    const float* lt   = (const float*)d_in[18];
    const float* lb   = (const float*)d_in[19];
    const float* pw   = (const float*)d_in[20];
    const float* pbi  = (const float*)d_in[21];
    const int*   rpi  = (const int*)d_in[22];

    if (ws_size < (size_t)26023936 * sizeof(float)) return;

    float* ws  = (float*)d_ws;
    float* qn  = ws;
    float* kvbuf = ws + 6422528;
    float* xs  = ws + 19267584;
    float* xp  = ws + 25690112;
    float* kvp = ws + 25790464;
    float* tab = ws + 25991168;
    float* out = (float*)d_out;

    unsigned short* ab   = (unsigned short*)xs;                  // bf16 attn out
    unsigned short* pwt  = (unsigned short*)(xs + 3211264);      // bf16 proj w^T
    unsigned short* xbf  = (unsigned short*)out;                 // bf16 x
    unsigned short* wcat = (unsigned short*)(out + 3211264);     // bf16 [q|kv|sr]^T

    dim3 blk(256);

    // prep: x->bf16, wcat, cpb table (one launch)
    prep_misc<<<7424, blk, 0, stream>>>(x, xbf, q_w, kv_w, sr_w, wcat,
                                        rct, f1w, f1b, f2w, f2b, tab);

    // fused q|kv|sr MFMA GEMM with fused L2-norm epilogue (norm for bn<512)
    gemm_bt<1><<<dim3(8, 196), blk, 0, stream>>>(xbf, wcat, q_b, kv_b, sr_b,
                                                 qn, kvbuf, xs);

    // 8x8 pool + LayerNorm -> fp32 xp (no pwt here — race removed)
    pool_ln<<<BATCH * PLEN, blk, 0, stream>>>(xs, ng, nb, xp);

    // pooled kv projection (fp32) + pwt transpose on extra grid row
    kvp_pwt<<<dim3(8, 8), blk, 0, stream>>>(xp, kv_w, kv_b, kvp, pw, pwt);

    // fused attention -> bf16 ab
    attn_tile<<<BATCH * NHEADS * WID * 2, blk, 0, stream>>>(
        qn, kvbuf, kvp, tab, rpi, qe, temp, sls, rpb, lt, lb, ab);

    // output projection (MFMA, no norm)
    gemm_bt<0><<<dim3(2, 196), blk, 0, stream>>>(ab, pwt, pbi, pbi, pbi,
                                                 out, out, out);
}